// Round 1
// baseline (23859.053 us; speedup 1.0000x reference)
//
#include <hip/hip_runtime.h>
#include <math.h>

// VGG_RP: 5x [conv3x3(pad1)+relu+maxpool2] -> RPN conv3x3(valid)+relu ->
//         {1x1 cls(sigmoid), 1x1 reg} -> deparam bboxes -> buggy-IoU greedy NMS
//         + FC(25088->20) on feat.
// Round 1: correct fp32 baseline (NCHW everywhere, matches reference layouts;
// the torch .view reshapes are memory no-ops so output sections are NCHW-flat).
//
// d_out layout (float32), out_size = 24640:
//   [0,640)        logits   [32,20]
//   [640,3040)     rp_cls   [32,75]   (NCHW flat of [32,3,5,5])
//   [3040,12640)   rp_reg   [32,300]  (NCHW flat of [32,12,5,5])
//   [12640,22240)  bboxes   [32,75,4]
//   [22240,24640)  keep     [32,75]   (0.0/1.0)
//
// d_ws usage: two ping-pong regions, total 154,140,672 bytes (~147 MB).

#define OFF_LOGITS 0
#define OFF_CLS    640
#define OFF_REG    3040
#define OFF_BOXES  12640
#define OFF_KEEP   22240

constexpr int BATCH = 32;
constexpr long A_ELEMS = 25690112L;  // 32*64*112*112 (largest "A" tenant)

// ---------------- conv3x3(pad1) + relu + maxpool2, direct fp32 ----------------
// One thread per pooled output element. Computes the 2x2 conv pixels from a
// 4x4 input window per cin, then max. relu(max+bias) == max(relu(.+bias)).
template<int CIN, int COUT, int HIN>
__global__ __launch_bounds__(256)
void conv_relu_pool(const float* __restrict__ in, const float* __restrict__ w,
                    const float* __restrict__ bias, float* __restrict__ out) {
  constexpr int WIN = HIN, HOUT = HIN / 2, WOUT = HIN / 2;
  const long total = (long)BATCH * COUT * HOUT * WOUT;
  long idx = (long)blockIdx.x * 256 + threadIdx.x;
  if (idx >= total) return;
  const int px = (int)(idx % WOUT);
  const int py = (int)((idx / WOUT) % HOUT);
  const int c  = (int)((idx / ((long)WOUT * HOUT)) % COUT);
  const int n  = (int)(idx / ((long)WOUT * HOUT * COUT));

  const float* __restrict__ ip = in + (long)n * CIN * HIN * WIN;
  const float* __restrict__ wp = w + (long)c * CIN * 9;

  float a00 = 0.f, a01 = 0.f, a10 = 0.f, a11 = 0.f;
  const int iy0 = 2 * py - 1, ix0 = 2 * px - 1;

  #pragma unroll 2
  for (int ci = 0; ci < CIN; ++ci) {
    const float* __restrict__ pl = ip + (long)ci * HIN * WIN;
    float win[4][4];
    #pragma unroll
    for (int r = 0; r < 4; ++r) {
      const int iy = iy0 + r;
      const bool yv = ((unsigned)iy < (unsigned)HIN);
      #pragma unroll
      for (int s = 0; s < 4; ++s) {
        const int ix = ix0 + s;
        win[r][s] = (yv && ((unsigned)ix < (unsigned)WIN)) ? pl[iy * WIN + ix] : 0.f;
      }
    }
    float wk[9];
    #pragma unroll
    for (int k = 0; k < 9; ++k) wk[k] = wp[ci * 9 + k];
    #pragma unroll
    for (int ky = 0; ky < 3; ++ky) {
      #pragma unroll
      for (int kx = 0; kx < 3; ++kx) {
        const float ww = wk[ky * 3 + kx];
        a00 = fmaf(win[ky    ][kx    ], ww, a00);
        a01 = fmaf(win[ky    ][kx + 1], ww, a01);
        a10 = fmaf(win[ky + 1][kx    ], ww, a10);
        a11 = fmaf(win[ky + 1][kx + 1], ww, a11);
      }
    }
  }
  const float m = fmaxf(fmaxf(a00, a01), fmaxf(a10, a11)) + bias[c];
  out[idx] = fmaxf(m, 0.f);  // idx == ((n*COUT+c)*HOUT+py)*WOUT+px (NCHW flat)
}

// ---------------- RPN conv: 512->512, 3x3 valid on 7x7 -> 5x5, relu ----------
__global__ __launch_bounds__(256)
void rpn_conv(const float* __restrict__ feat, const float* __restrict__ w,
              const float* __restrict__ bias, float* __restrict__ out) {
  const int idx = blockIdx.x * 256 + threadIdx.x;
  if (idx >= BATCH * 512 * 25) return;
  const int px = idx % 5, py = (idx / 5) % 5;
  const int c = (idx / 25) % 512, n = idx / (25 * 512);
  const float* __restrict__ ip = feat + (long)n * 512 * 49 + py * 7 + px;
  const float* __restrict__ wp = w + (long)c * 512 * 9;
  float acc = 0.f;
  for (int ci = 0; ci < 512; ++ci) {
    const float* __restrict__ pl = ip + ci * 49;
    const float* __restrict__ wk = wp + ci * 9;
    acc = fmaf(pl[0],  wk[0], acc); acc = fmaf(pl[1],  wk[1], acc); acc = fmaf(pl[2],  wk[2], acc);
    acc = fmaf(pl[7],  wk[3], acc); acc = fmaf(pl[8],  wk[4], acc); acc = fmaf(pl[9],  wk[5], acc);
    acc = fmaf(pl[14], wk[6], acc); acc = fmaf(pl[15], wk[7], acc); acc = fmaf(pl[16], wk[8], acc);
  }
  out[idx] = fmaxf(acc + bias[c], 0.f);
}

// ---------------- 1x1 heads: cls (sigmoid) + reg, write straight to d_out ----
__global__ __launch_bounds__(256)
void heads_kernel(const float* __restrict__ rp512,
                  const float* __restrict__ cls_w, const float* __restrict__ cls_b,
                  const float* __restrict__ reg_w, const float* __restrict__ reg_b,
                  float* __restrict__ out) {
  const int n = blockIdx.x;
  const float* __restrict__ ip = rp512 + (long)n * 512 * 25;
  for (int p = threadIdx.x; p < 375; p += 256) {
    const int o = p / 25, pix = p % 25;
    const float* __restrict__ wv = (o < 3) ? (cls_w + o * 512) : (reg_w + (o - 3) * 512);
    float acc = 0.f;
    for (int ci = 0; ci < 512; ++ci) acc = fmaf(ip[ci * 25 + pix], wv[ci], acc);
    if (o < 3) {
      acc += cls_b[o];
      out[OFF_CLS + n * 75 + o * 25 + pix] = 1.f / (1.f + expf(-acc));
    } else {
      acc += reg_b[o - 3];
      out[OFF_REG + n * 300 + (o - 3) * 25 + pix] = acc;
    }
  }
}

// ---------------- FC: feat(NCHW flat 25088) @ fc_w.T + fc_b ------------------
__global__ __launch_bounds__(256)
void fc_kernel(const float* __restrict__ feat, const float* __restrict__ fw,
               const float* __restrict__ fb, float* __restrict__ out) {
  const int n = blockIdx.x;
  __shared__ float red[256];
  const float* __restrict__ ip = feat + (long)n * 25088;
  for (int j = 0; j < 20; ++j) {
    const float* __restrict__ wj = fw + (long)j * 25088;
    float acc = 0.f;
    for (int k = threadIdx.x; k < 25088; k += 256) acc = fmaf(ip[k], wj[k], acc);
    red[threadIdx.x] = acc;
    __syncthreads();
    for (int s = 128; s > 0; s >>= 1) {
      if (threadIdx.x < s) red[threadIdx.x] += red[threadIdx.x + s];
      __syncthreads();
    }
    if (threadIdx.x == 0) out[OFF_LOGITS + n * 20 + j] = red[0] + fb[j];
    __syncthreads();
  }
}

// ---------------- deparam bboxes + faithful buggy-IoU greedy NMS -------------
// One block per batch. Stable-descending rank (ties -> lower index first)
// replicates jnp.argsort(-scores). IoU formula replicated EXACTLY:
// inter/areaA + areaB - inter   (missing-parens bug).
__global__ __launch_bounds__(128)
void bbox_nms_kernel(float* __restrict__ out) {
  const int n = blockIdx.x;
  const int t = threadIdx.x;
  __shared__ float bx0[75], by0[75], bx1[75], by1[75], area[75], sc[75];
  __shared__ int rank_s[75], order_s[75], keep_s[75];

  if (t < 75) {
    const int g1 = t / 15, g2 = (t / 3) % 5, a = t % 3;
    const float aw = (a == 0) ? 56.f : (a == 1 ? 112.f : 224.f);
    const float r0 = out[OFF_REG + n * 300 + 4 * t + 0];
    const float r1 = out[OFF_REG + n * 300 + 4 * t + 1];
    const float r2 = out[OFF_REG + n * 300 + 4 * t + 2];
    const float r3 = out[OFF_REG + n * 300 + 4 * t + 3];
    const float cx = r0 * aw + (float)g1;
    const float cy = r1 * aw + (float)g2;
    const float w_ = expf(r2) * aw;
    const float h_ = expf(r3) * aw;
    const float x0 = cx - 0.5f * w_, y0 = cy - 0.5f * h_;
    const float x1 = cx + 0.5f * w_, y1 = cy + 0.5f * h_;
    bx0[t] = x0; by0[t] = y0; bx1[t] = x1; by1[t] = y1;
    area[t] = (x1 - x0 + 1.f) * (y1 - y0 + 1.f);
    out[OFF_BOXES + n * 300 + 4 * t + 0] = x0;
    out[OFF_BOXES + n * 300 + 4 * t + 1] = y0;
    out[OFF_BOXES + n * 300 + 4 * t + 2] = x1;
    out[OFF_BOXES + n * 300 + 4 * t + 3] = y1;
    sc[t] = out[OFF_CLS + n * 75 + t];
    keep_s[t] = 1;
  }
  __syncthreads();
  if (t < 75) {
    const float si = sc[t];
    int rk = 0;
    for (int j = 0; j < 75; ++j) {
      const float sj = sc[j];
      rk += (sj > si) || (sj == si && j < t);
    }
    rank_s[t] = rk;
    order_s[rk] = t;
  }
  __syncthreads();
  for (int i = 0; i < 74; ++i) {
    if (keep_s[i]) {  // uniform branch; keep_s[i] only written in iters < i
      const int bi = order_s[i];
      if (t > i && t < 75) {
        const int bj = order_s[t];
        const float xA = fmaxf(bx0[bi], bx0[bj]);
        const float yA = fmaxf(by0[bi], by0[bj]);
        const float xB = fminf(bx1[bi], bx1[bj]);
        const float yB = fminf(by1[bi], by1[bj]);
        const float inter = fmaxf(0.f, xB - xA + 1.f) * fmaxf(0.f, yB - yA + 1.f);
        const float iou = inter / area[bi] + area[bj] - inter;  // the bug, faithfully
        if (iou > 0.7f) keep_s[t] = 0;
      }
    }
    __syncthreads();
  }
  if (t < 75) out[OFF_KEEP + n * 75 + t] = keep_s[rank_s[t]] ? 1.f : 0.f;
}

// ------------------------------- launch --------------------------------------
extern "C" void kernel_launch(void* const* d_in, const int* in_sizes, int n_in,
                              void* d_out, int out_size, void* d_ws, size_t ws_size,
                              hipStream_t stream) {
  (void)in_sizes; (void)n_in; (void)out_size; (void)ws_size;
  const float* x     = (const float*)d_in[0];
  const float* fw0   = (const float*)d_in[1];
  const float* fb0   = (const float*)d_in[2];
  const float* fw1   = (const float*)d_in[3];
  const float* fb1   = (const float*)d_in[4];
  const float* fw2   = (const float*)d_in[5];
  const float* fb2   = (const float*)d_in[6];
  const float* fw3   = (const float*)d_in[7];
  const float* fb3   = (const float*)d_in[8];
  const float* fw4   = (const float*)d_in[9];
  const float* fb4   = (const float*)d_in[10];
  const float* rpw_w = (const float*)d_in[11];
  const float* rpw_b = (const float*)d_in[12];
  const float* cls_w = (const float*)d_in[13];
  const float* cls_b = (const float*)d_in[14];
  const float* reg_w = (const float*)d_in[15];
  const float* reg_b = (const float*)d_in[16];
  const float* fc_w  = (const float*)d_in[17];
  const float* fc_b  = (const float*)d_in[18];
  float* out = (float*)d_out;

  // Ping-pong scratch: A then B, strictly alternating producers/consumers.
  float* A  = (float*)d_ws;           // p0 [32,64,112,112] -> p2 -> p4(feat)
  float* Bb = A + A_ELEMS;            // p1 [32,128,56,56] -> p3 -> rp512

  conv_relu_pool<3,   64, 224><<<(25690112 + 255) / 256, 256, 0, stream>>>(x,  fw0, fb0, A);
  conv_relu_pool<64, 128, 112><<<(12845056 + 255) / 256, 256, 0, stream>>>(A,  fw1, fb1, Bb);
  conv_relu_pool<128,256,  56><<<( 6422528 + 255) / 256, 256, 0, stream>>>(Bb, fw2, fb2, A);
  conv_relu_pool<256,512,  28><<<( 3211264 + 255) / 256, 256, 0, stream>>>(A,  fw3, fb3, Bb);
  conv_relu_pool<512,512,  14><<<(  802816 + 255) / 256, 256, 0, stream>>>(Bb, fw4, fb4, A);

  rpn_conv<<<1600, 256, 0, stream>>>(A, rpw_w, rpw_b, Bb);
  heads_kernel<<<BATCH, 256, 0, stream>>>(Bb, cls_w, cls_b, reg_w, reg_b, out);
  fc_kernel<<<BATCH, 256, 0, stream>>>(A, fc_w, fc_b, out);
  bbox_nms_kernel<<<BATCH, 128, 0, stream>>>(out);
}

// Round 2
// 3232.015 us; speedup vs baseline: 7.3821x; 7.3821x over previous
//
#include <hip/hip_runtime.h>
#include <math.h>

// VGG_RP round 2: split-fp16 MFMA implicit-GEMM conv (hi/lo, 3 products ->
// ~2^-22 rel error, fp32-class) for layers 1-4 + RPN; fused bias/relu/2x2-pool
// epilogue that also emits next layer's channels-last fp16 hi/lo input.
// L0 (cin=3) = direct fp32 conv with LDS tile. heads/fc/nms as round 1.
//
// d_out (float32), out_size = 24640:
//   [0,640) logits | [640,3040) rp_cls | [3040,12640) rp_reg
//   [12640,22240) bboxes | [22240,24640) keep

#define OFF_LOGITS 0
#define OFF_CLS    640
#define OFF_REG    3040
#define OFF_BOXES  12640
#define OFF_KEEP   22240

constexpr int BATCH = 32;

typedef _Float16 h8 __attribute__((ext_vector_type(8)));
typedef _Float16 h4 __attribute__((ext_vector_type(4)));
typedef float    f4 __attribute__((ext_vector_type(4)));

#define MFMA16(a, b, c) __builtin_amdgcn_mfma_f32_16x16x32_f16(a, b, c, 0, 0, 0)

// ---------------- workspace layout (bytes) ----------------
// Region A (reused): I0 -> I2 -> {I4, feat, rp512}
// Region B (reused): I1 -> I3
// Region W: converted weights
constexpr size_t A_OFF = 0;                      // 106,463,232 B
constexpr size_t B_OFF = 106463232;              // 55,115,776 B
constexpr size_t W_OFF = 161579008;              // 25,067,520 B -> total ~186.6 MB

// elems per plane
constexpr int I0_E = 32 * 114 * 114 * 64;    // 26,615,808
constexpr int I1_E = 32 * 58 * 58 * 128;     // 13,778,944
constexpr int I2_E = 32 * 30 * 30 * 256;     //  7,372,800
constexpr int I3_E = 32 * 16 * 16 * 512;     //  4,194,304
constexpr int I4_E = 32 * 7 * 7 * 512;       //    802,816

// ---------------- weight convert: OIHW fp32 -> [tap][co][ci] fp16 hi/lo -----
__global__ __launch_bounds__(256)
void wcvt(const float* __restrict__ src, _Float16* __restrict__ dHi,
          _Float16* __restrict__ dLo, int COUT, int CIN) {
  const int total = COUT * CIN * 9;
  for (int idx = blockIdx.x * 256 + threadIdx.x; idx < total; idx += gridDim.x * 256) {
    const int co = idx / (CIN * 9);
    const int r = idx % (CIN * 9);
    const int ci = r / 9, tap = r % 9;
    const float v = src[idx];
    const _Float16 h = (_Float16)v;
    const int o = (tap * COUT + co) * CIN + ci;
    dHi[o] = h;
    dLo[o] = (_Float16)(v - (float)h);
  }
}

// ---------------- zero the 1-px pad ring of a CL fp16 buffer ----------------
__global__ __launch_bounds__(256)
void zero_ring(_Float16* __restrict__ hi, _Float16* __restrict__ lo, int P, int C) {
  const int c8n = C / 8, cells = 4 * P - 4;
  const int tot = 32 * cells * c8n;
  for (int idx = blockIdx.x * 256 + threadIdx.x; idx < tot; idx += gridDim.x * 256) {
    const int c8 = idx % c8n;
    const int cell = (idx / c8n) % cells;
    const int n = idx / (c8n * cells);
    int y, xx;
    if (cell < 2 * P) { y = (cell < P) ? 0 : (P - 1); xx = cell % P; }
    else { const int q = cell - 2 * P; y = 1 + (q >> 1); xx = (q & 1) ? (P - 1) : 0; }
    const long o = ((long)(n * P + y) * P + xx) * C + c8 * 8;
    h8 z = {};
    *reinterpret_cast<h8*>(hi + o) = z;
    *reinterpret_cast<h8*>(lo + o) = z;
  }
}

// ---------------- L0: 3->64 direct fp32 conv+pool, emit fp16 CL padded ------
__global__ __launch_bounds__(256)
void conv_l0(const float* __restrict__ x, const float* __restrict__ w0,
             const float* __restrict__ b0, _Float16* __restrict__ outHi,
             _Float16* __restrict__ outLo) {
  const int bid = blockIdx.x;
  const int tx0 = (bid % 7) * 16, ty0 = ((bid / 7) % 7) * 16, n = bid / 49;
  __shared__ float sIn[3 * 34 * 34];
  __shared__ float sW[1728];
  __shared__ float sB[64];
  const int tid = threadIdx.x;
  for (int idx = tid; idx < 3 * 34 * 34; idx += 256) {
    const int ci = idx / 1156, rem = idx % 1156, r = rem / 34, cc = rem % 34;
    const int y = 2 * ty0 - 1 + r, xx = 2 * tx0 - 1 + cc;
    float v = 0.f;
    if ((unsigned)y < 224u && (unsigned)xx < 224u)
      v = x[((n * 3 + ci) * 224 + y) * 224 + xx];
    sIn[idx] = v;
  }
  for (int idx = tid; idx < 1728; idx += 256) sW[idx] = w0[idx];
  if (tid < 64) sB[tid] = b0[tid];
  __syncthreads();

  const int tpy = tid / 16, tpx = tid % 16;
  float win[3][4][4];
  #pragma unroll
  for (int ci = 0; ci < 3; ++ci)
    #pragma unroll
    for (int dr = 0; dr < 4; ++dr)
      #pragma unroll
      for (int dc = 0; dc < 4; ++dc)
        win[ci][dr][dc] = sIn[ci * 1156 + (2 * tpy + dr) * 34 + (2 * tpx + dc)];

  const long ob = ((long)(n * 114 + ty0 + tpy + 1) * 114 + tx0 + tpx + 1) * 64;
  for (int co4 = 0; co4 < 16; ++co4) {
    h4 hh, ll;
    #pragma unroll
    for (int j = 0; j < 4; ++j) {
      const int co = co4 * 4 + j;
      float a00 = 0.f, a01 = 0.f, a10 = 0.f, a11 = 0.f;
      #pragma unroll
      for (int ci = 0; ci < 3; ++ci)
        #pragma unroll
        for (int ky = 0; ky < 3; ++ky)
          #pragma unroll
          for (int kx = 0; kx < 3; ++kx) {
            const float wv = sW[co * 27 + ci * 9 + ky * 3 + kx];
            a00 = fmaf(win[ci][ky][kx], wv, a00);
            a01 = fmaf(win[ci][ky][kx + 1], wv, a01);
            a10 = fmaf(win[ci][ky + 1][kx], wv, a10);
            a11 = fmaf(win[ci][ky + 1][kx + 1], wv, a11);
          }
      const float p = fmaxf(fmaxf(fmaxf(a00, a01), fmaxf(a10, a11)) + sB[co], 0.f);
      const _Float16 h = (_Float16)p;
      hh[j] = h;
      ll[j] = (_Float16)(p - (float)h);
    }
    *reinterpret_cast<h4*>(outHi + ob + co4 * 4) = hh;
    *reinterpret_cast<h4*>(outLo + ob + co4 * 4) = ll;
  }
}

// ---------------- main conv+pool implicit GEMM (split-fp16, 3-product) ------
// in: CL padded [n][H+2][W+2][CIN] hi/lo. w: [9][COUT][CIN] hi/lo.
// out: pooled, CL (PADOUT? padded : tight) hi/lo; optionally fp32 NCHW (L4).
// Block: 4 waves, co 128 x sp 64. Wave: co 32 x sp 64 (2x4 MFMA tiles).
// Spatial flat s = ((n*Hp+py)*W + x)*2 + ry ; groups of 4 s = one 2x2 pool win.
template<int CIN, int COUT, int H, int PADOUT, int WF32>
__global__ __launch_bounds__(256)
void convpool(const _Float16* __restrict__ inHi, const _Float16* __restrict__ inLo,
              const _Float16* __restrict__ wHi, const _Float16* __restrict__ wLo,
              const float* __restrict__ bias, _Float16* __restrict__ outHi,
              _Float16* __restrict__ outLo, float* __restrict__ outF) {
  constexpr int W = H, Hp = H / 2, Wp = W / 2, PW = W + 2, POW = Wp + 2;
  const int lane = threadIdx.x & 63, wv = threadIdx.x >> 6;
  const int cow = blockIdx.y * 128 + wv * 32;
  const int sblk = blockIdx.x * 64;
  const int c = lane & 15, kq = lane >> 4, kof = kq * 8;

  int baseB[4];
  #pragma unroll
  for (int nt = 0; nt < 4; ++nt) {
    const int s = sblk + nt * 16 + c;
    const int ry = s & 1, t = s >> 1;
    const int x = t % W, u = t / W;
    const int py = u % Hp, n = u / Hp;
    const int y = 2 * py + ry;
    baseB[nt] = ((n * (H + 2) + y) * PW + x) * CIN;
  }
  const int baseA0 = (cow + c) * CIN;
  const int baseA1 = (cow + 16 + c) * CIN;

  f4 acc[2][4] = {};
  for (int tap = 0; tap < 9; ++tap) {
    const int ky = tap / 3, kx = tap % 3;
    const int tb = (ky * PW + kx) * CIN;
    const int ta = tap * COUT * CIN;
    for (int kc = 0; kc < CIN; kc += 32) {
      h8 aH[2], aL[2], bH[4], bL[4];
      const int ao0 = ta + baseA0 + kc + kof, ao1 = ta + baseA1 + kc + kof;
      aH[0] = *reinterpret_cast<const h8*>(wHi + ao0);
      aL[0] = *reinterpret_cast<const h8*>(wLo + ao0);
      aH[1] = *reinterpret_cast<const h8*>(wHi + ao1);
      aL[1] = *reinterpret_cast<const h8*>(wLo + ao1);
      #pragma unroll
      for (int nt = 0; nt < 4; ++nt) {
        const int bo = baseB[nt] + tb + kc + kof;
        bH[nt] = *reinterpret_cast<const h8*>(inHi + bo);
        bL[nt] = *reinterpret_cast<const h8*>(inLo + bo);
      }
      #pragma unroll
      for (int mt = 0; mt < 2; ++mt)
        #pragma unroll
        for (int nt = 0; nt < 4; ++nt)
          acc[mt][nt] = MFMA16(aH[mt], bH[nt], acc[mt][nt]);
      #pragma unroll
      for (int mt = 0; mt < 2; ++mt)
        #pragma unroll
        for (int nt = 0; nt < 4; ++nt)
          acc[mt][nt] = MFMA16(aH[mt], bL[nt], acc[mt][nt]);
      #pragma unroll
      for (int mt = 0; mt < 2; ++mt)
        #pragma unroll
        for (int nt = 0; nt < 4; ++nt)
          acc[mt][nt] = MFMA16(aL[mt], bH[nt], acc[mt][nt]);
    }
  }

  // epilogue: 2x2 pool across col groups of 4, bias+relu, hi/lo CL write
  const int r4 = lane >> 4;
  #pragma unroll
  for (int mt = 0; mt < 2; ++mt) {
    const int co0 = cow + mt * 16 + r4 * 4;
    const f4 bi = *reinterpret_cast<const f4*>(bias + co0);
    #pragma unroll
    for (int nt = 0; nt < 4; ++nt) {
      f4 v = acc[mt][nt];
      #pragma unroll
      for (int r = 0; r < 4; ++r) {
        const float m1 = fmaxf(v[r], __shfl_xor(v[r], 1, 64));
        v[r] = fmaxf(m1, __shfl_xor(m1, 2, 64));
      }
      if ((lane & 3) == 0) {
        const int s = sblk + nt * 16 + c;
        const int ps = s >> 2;
        const int n = ps / (Hp * Wp), rem = ps % (Hp * Wp);
        const int py = rem / Wp, px = rem % Wp;
        h4 hh, ll;
        float fv[4];
        #pragma unroll
        for (int r = 0; r < 4; ++r) {
          const float p = fmaxf(v[r] + bi[r], 0.f);
          const _Float16 h = (_Float16)p;
          hh[r] = h;
          ll[r] = (_Float16)(p - (float)h);
          fv[r] = p;
        }
        const long oa = PADOUT
            ? ((long)((n * (Hp + 2) + py + 1) * POW + px + 1)) * COUT + co0
            : ((long)((n * Hp + py) * Wp + px)) * COUT + co0;
        *reinterpret_cast<h4*>(outHi + oa) = hh;
        *reinterpret_cast<h4*>(outLo + oa) = ll;
        if (WF32) {
          #pragma unroll
          for (int r = 0; r < 4; ++r)
            outF[((long)(n * COUT + co0 + r) * Hp + py) * Wp + px] = fv[r];
        }
      }
    }
  }
}

// ---------------- RPN: 512->512 3x3 valid on 7x7 -> 5x5, split-fp16 GEMM ----
__global__ __launch_bounds__(256)
void rpn_gemm(const _Float16* __restrict__ inHi, const _Float16* __restrict__ inLo,
              const _Float16* __restrict__ wHi, const _Float16* __restrict__ wLo,
              const float* __restrict__ bias, float* __restrict__ rp512) {
  const int lane = threadIdx.x & 63, wv = threadIdx.x >> 6;
  const int cow = blockIdx.y * 128 + wv * 32;
  const int sblk = blockIdx.x * 64;
  const int c = lane & 15, kq = lane >> 4, kof = kq * 8;

  int baseB[4];
  #pragma unroll
  for (int nt = 0; nt < 4; ++nt) {
    int s = sblk + nt * 16 + c;
    if (s > 799) s = 799;
    const int n = s / 25, pix = s % 25, py = pix / 5, px = pix % 5;
    baseB[nt] = ((n * 7 + py) * 7 + px) * 512;
  }
  const int baseA0 = (cow + c) * 512;
  const int baseA1 = (cow + 16 + c) * 512;

  f4 acc[2][4] = {};
  for (int tap = 0; tap < 9; ++tap) {
    const int ky = tap / 3, kx = tap % 3;
    const int tb = (ky * 7 + kx) * 512;
    const int ta = tap * 512 * 512;
    for (int kc = 0; kc < 512; kc += 32) {
      h8 aH[2], aL[2], bH[4], bL[4];
      const int ao0 = ta + baseA0 + kc + kof, ao1 = ta + baseA1 + kc + kof;
      aH[0] = *reinterpret_cast<const h8*>(wHi + ao0);
      aL[0] = *reinterpret_cast<const h8*>(wLo + ao0);
      aH[1] = *reinterpret_cast<const h8*>(wHi + ao1);
      aL[1] = *reinterpret_cast<const h8*>(wLo + ao1);
      #pragma unroll
      for (int nt = 0; nt < 4; ++nt) {
        const int bo = baseB[nt] + tb + kc + kof;
        bH[nt] = *reinterpret_cast<const h8*>(inHi + bo);
        bL[nt] = *reinterpret_cast<const h8*>(inLo + bo);
      }
      #pragma unroll
      for (int mt = 0; mt < 2; ++mt)
        #pragma unroll
        for (int nt = 0; nt < 4; ++nt)
          acc[mt][nt] = MFMA16(aH[mt], bH[nt], acc[mt][nt]);
      #pragma unroll
      for (int mt = 0; mt < 2; ++mt)
        #pragma unroll
        for (int nt = 0; nt < 4; ++nt)
          acc[mt][nt] = MFMA16(aH[mt], bL[nt], acc[mt][nt]);
      #pragma unroll
      for (int mt = 0; mt < 2; ++mt)
        #pragma unroll
        for (int nt = 0; nt < 4; ++nt)
          acc[mt][nt] = MFMA16(aL[mt], bH[nt], acc[mt][nt]);
    }
  }

  const int r4 = lane >> 4;
  #pragma unroll
  for (int mt = 0; mt < 2; ++mt) {
    const int co0 = cow + mt * 16 + r4 * 4;
    const f4 bi = *reinterpret_cast<const f4*>(bias + co0);
    #pragma unroll
    for (int nt = 0; nt < 4; ++nt) {
      const int s = sblk + nt * 16 + c;
      if (s < 800) {
        const int n = s / 25, pix = s % 25;
        #pragma unroll
        for (int r = 0; r < 4; ++r)
          rp512[((long)(n * 512 + co0 + r)) * 25 + pix] =
              fmaxf(acc[mt][nt][r] + bi[r], 0.f);
      }
    }
  }
}

// ---------------- 1x1 heads (fp32), straight to d_out -----------------------
__global__ __launch_bounds__(256)
void heads_kernel(const float* __restrict__ rp512,
                  const float* __restrict__ cls_w, const float* __restrict__ cls_b,
                  const float* __restrict__ reg_w, const float* __restrict__ reg_b,
                  float* __restrict__ out) {
  const int n = blockIdx.x;
  const float* __restrict__ ip = rp512 + (long)n * 512 * 25;
  for (int p = threadIdx.x; p < 375; p += 256) {
    const int o = p / 25, pix = p % 25;
    const float* __restrict__ wvp = (o < 3) ? (cls_w + o * 512) : (reg_w + (o - 3) * 512);
    float acc = 0.f;
    for (int ci = 0; ci < 512; ++ci) acc = fmaf(ip[ci * 25 + pix], wvp[ci], acc);
    if (o < 3) {
      acc += cls_b[o];
      out[OFF_CLS + n * 75 + o * 25 + pix] = 1.f / (1.f + expf(-acc));
    } else {
      acc += reg_b[o - 3];
      out[OFF_REG + n * 300 + (o - 3) * 25 + pix] = acc;
    }
  }
}

// ---------------- FC: feat(NCHW flat 25088) @ fc_w.T + fc_b ------------------
__global__ __launch_bounds__(256)
void fc_kernel(const float* __restrict__ feat, const float* __restrict__ fw,
               const float* __restrict__ fb, float* __restrict__ out) {
  const int n = blockIdx.x;
  __shared__ float red[256];
  const float* __restrict__ ip = feat + (long)n * 25088;
  for (int j = 0; j < 20; ++j) {
    const float* __restrict__ wj = fw + (long)j * 25088;
    float acc = 0.f;
    for (int k = threadIdx.x; k < 25088; k += 256) acc = fmaf(ip[k], wj[k], acc);
    red[threadIdx.x] = acc;
    __syncthreads();
    for (int s = 128; s > 0; s >>= 1) {
      if (threadIdx.x < s) red[threadIdx.x] += red[threadIdx.x + s];
      __syncthreads();
    }
    if (threadIdx.x == 0) out[OFF_LOGITS + n * 20 + j] = red[0] + fb[j];
    __syncthreads();
  }
}

// ---------------- deparam bboxes + faithful buggy-IoU greedy NMS -------------
__global__ __launch_bounds__(128)
void bbox_nms_kernel(float* __restrict__ out) {
  const int n = blockIdx.x;
  const int t = threadIdx.x;
  __shared__ float bx0[75], by0[75], bx1[75], by1[75], area[75], sc[75];
  __shared__ int rank_s[75], order_s[75], keep_s[75];

  if (t < 75) {
    const int g1 = t / 15, g2 = (t / 3) % 5, a = t % 3;
    const float aw = (a == 0) ? 56.f : (a == 1 ? 112.f : 224.f);
    const float r0 = out[OFF_REG + n * 300 + 4 * t + 0];
    const float r1 = out[OFF_REG + n * 300 + 4 * t + 1];
    const float r2 = out[OFF_REG + n * 300 + 4 * t + 2];
    const float r3 = out[OFF_REG + n * 300 + 4 * t + 3];
    const float cx = r0 * aw + (float)g1;
    const float cy = r1 * aw + (float)g2;
    const float w_ = expf(r2) * aw;
    const float h_ = expf(r3) * aw;
    const float x0 = cx - 0.5f * w_, y0 = cy - 0.5f * h_;
    const float x1 = cx + 0.5f * w_, y1 = cy + 0.5f * h_;
    bx0[t] = x0; by0[t] = y0; bx1[t] = x1; by1[t] = y1;
    area[t] = (x1 - x0 + 1.f) * (y1 - y0 + 1.f);
    out[OFF_BOXES + n * 300 + 4 * t + 0] = x0;
    out[OFF_BOXES + n * 300 + 4 * t + 1] = y0;
    out[OFF_BOXES + n * 300 + 4 * t + 2] = x1;
    out[OFF_BOXES + n * 300 + 4 * t + 3] = y1;
    sc[t] = out[OFF_CLS + n * 75 + t];
    keep_s[t] = 1;
  }
  __syncthreads();
  if (t < 75) {
    const float si = sc[t];
    int rk = 0;
    for (int j = 0; j < 75; ++j) {
      const float sj = sc[j];
      rk += (sj > si) || (sj == si && j < t);
    }
    rank_s[t] = rk;
    order_s[rk] = t;
  }
  __syncthreads();
  for (int i = 0; i < 74; ++i) {
    if (keep_s[i]) {
      const int bi = order_s[i];
      if (t > i && t < 75) {
        const int bj = order_s[t];
        const float xA = fmaxf(bx0[bi], bx0[bj]);
        const float yA = fmaxf(by0[bi], by0[bj]);
        const float xB = fminf(bx1[bi], bx1[bj]);
        const float yB = fminf(by1[bi], by1[bj]);
        const float inter = fmaxf(0.f, xB - xA + 1.f) * fmaxf(0.f, yB - yA + 1.f);
        const float iou = inter / area[bi] + area[bj] - inter;  // faithful bug
        if (iou > 0.7f) keep_s[t] = 0;
      }
    }
    __syncthreads();
  }
  if (t < 75) out[OFF_KEEP + n * 75 + t] = keep_s[rank_s[t]] ? 1.f : 0.f;
}

// ------------------------------- launch --------------------------------------
extern "C" void kernel_launch(void* const* d_in, const int* in_sizes, int n_in,
                              void* d_out, int out_size, void* d_ws, size_t ws_size,
                              hipStream_t stream) {
  (void)in_sizes; (void)n_in; (void)out_size; (void)ws_size;
  const float* x     = (const float*)d_in[0];
  const float* fw0   = (const float*)d_in[1];
  const float* fb0   = (const float*)d_in[2];
  const float* fw1   = (const float*)d_in[3];
  const float* fb1   = (const float*)d_in[4];
  const float* fw2   = (const float*)d_in[5];
  const float* fb2   = (const float*)d_in[6];
  const float* fw3   = (const float*)d_in[7];
  const float* fb3   = (const float*)d_in[8];
  const float* fw4   = (const float*)d_in[9];
  const float* fb4   = (const float*)d_in[10];
  const float* rpw_w = (const float*)d_in[11];
  const float* rpw_b = (const float*)d_in[12];
  const float* cls_w = (const float*)d_in[13];
  const float* cls_b = (const float*)d_in[14];
  const float* reg_w = (const float*)d_in[15];
  const float* reg_b = (const float*)d_in[16];
  const float* fc_w  = (const float*)d_in[17];
  const float* fc_b  = (const float*)d_in[18];
  float* out = (float*)d_out;
  char* ws = (char*)d_ws;

  // activation buffers (fp16 hi/lo planes)
  _Float16* I0h = (_Float16*)(ws + A_OFF);
  _Float16* I0l = I0h + I0_E;
  _Float16* I1h = (_Float16*)(ws + B_OFF);
  _Float16* I1l = I1h + I1_E;
  _Float16* I2h = (_Float16*)(ws + A_OFF);
  _Float16* I2l = I2h + I2_E;
  _Float16* I3h = (_Float16*)(ws + B_OFF);
  _Float16* I3l = I3h + I3_E;
  _Float16* I4h = (_Float16*)(ws + A_OFF);
  _Float16* I4l = I4h + I4_E;
  float* feat  = (float*)(ws + A_OFF + (size_t)I4_E * 4);            // after I4 hi+lo
  float* rp512 = (float*)(ws + A_OFF + (size_t)I4_E * 4 + 3211264);  // after feat

  // converted weights [tap][co][ci] hi/lo
  _Float16* w1h = (_Float16*)(ws + W_OFF);                _Float16* w1l = w1h + 73728;
  _Float16* w2h = (_Float16*)(ws + W_OFF + 294912);       _Float16* w2l = w2h + 294912;
  _Float16* w3h = (_Float16*)(ws + W_OFF + 1474560);      _Float16* w3l = w3h + 1179648;
  _Float16* w4h = (_Float16*)(ws + W_OFF + 6193152);      _Float16* w4l = w4h + 2359296;
  _Float16* wrh = (_Float16*)(ws + W_OFF + 15630336);     _Float16* wrl = wrh + 2359296;

  // weight conversion
  wcvt<<<(73728 + 255) / 256, 256, 0, stream>>>(fw1, w1h, w1l, 128, 64);
  wcvt<<<(294912 + 255) / 256, 256, 0, stream>>>(fw2, w2h, w2l, 256, 128);
  wcvt<<<(1179648 + 255) / 256, 256, 0, stream>>>(fw3, w3h, w3l, 512, 256);
  wcvt<<<(2359296 + 255) / 256, 256, 0, stream>>>(fw4, w4h, w4l, 512, 512);
  wcvt<<<(2359296 + 255) / 256, 256, 0, stream>>>(rpw_w, wrh, wrl, 512, 512);

  // pad rings for I0, I1 (regions free now)
  zero_ring<<<512, 256, 0, stream>>>(I0h, I0l, 114, 64);
  zero_ring<<<512, 256, 0, stream>>>(I1h, I1l, 58, 128);

  // L0 direct conv
  conv_l0<<<32 * 49, 256, 0, stream>>>(x, fw0, fb0, I0h, I0l);

  // L1: 64->128 @112 ; writes I1 (padded CL)
  convpool<64, 128, 112, 1, 0><<<dim3(6272, 1), 256, 0, stream>>>(
      I0h, I0l, w1h, w1l, fb1, I1h, I1l, nullptr);
  zero_ring<<<512, 256, 0, stream>>>(I2h, I2l, 30, 256);   // I0 region now free
  // L2: 128->256 @56
  convpool<128, 256, 56, 1, 0><<<dim3(1568, 2), 256, 0, stream>>>(
      I1h, I1l, w2h, w2l, fb2, I2h, I2l, nullptr);
  zero_ring<<<512, 256, 0, stream>>>(I3h, I3l, 16, 512);   // I1 region now free
  // L3: 256->512 @28
  convpool<256, 512, 28, 1, 0><<<dim3(392, 4), 256, 0, stream>>>(
      I2h, I2l, w3h, w3l, fb3, I3h, I3l, nullptr);
  // L4: 512->512 @14 ; writes I4 (tight CL) + feat (fp32 NCHW)
  convpool<512, 512, 14, 0, 1><<<dim3(98, 4), 256, 0, stream>>>(
      I3h, I3l, w4h, w4l, fb4, I4h, I4l, feat);

  // RPN + heads + fc + nms
  rpn_gemm<<<dim3(13, 4), 256, 0, stream>>>(I4h, I4l, wrh, wrl, rpw_b, rp512);
  heads_kernel<<<BATCH, 256, 0, stream>>>(rp512, cls_w, cls_b, reg_w, reg_b, out);
  fc_kernel<<<BATCH, 256, 0, stream>>>(feat, fc_w, fc_b, out);
  bbox_nms_kernel<<<BATCH, 128, 0, stream>>>(out);
}

// Round 3
// 2225.885 us; speedup vs baseline: 10.7189x; 1.4520x over previous
//
#include <hip/hip_runtime.h>
#include <math.h>

// VGG_RP round 3: split-fp16 MFMA implicit-GEMM conv (hi/lo, 3 products ->
// fp32-class accuracy) with co64xsp64 wave tiles (0.33 loads/MFMA);
// parallel FC (grid 32x20); channels-last rp512 + parallel heads.
// L0 (cin=3) = direct fp32 conv with LDS tile. nms as round 1 (passed).
//
// d_out (float32), out_size = 24640:
//   [0,640) logits | [640,3040) rp_cls | [3040,12640) rp_reg
//   [12640,22240) bboxes | [22240,24640) keep

#define OFF_LOGITS 0
#define OFF_CLS    640
#define OFF_REG    3040
#define OFF_BOXES  12640
#define OFF_KEEP   22240

constexpr int BATCH = 32;

typedef _Float16 h8 __attribute__((ext_vector_type(8)));
typedef _Float16 h4 __attribute__((ext_vector_type(4)));
typedef float    f4 __attribute__((ext_vector_type(4)));

#define MFMA16(a, b, c) __builtin_amdgcn_mfma_f32_16x16x32_f16(a, b, c, 0, 0, 0)

// ---------------- workspace layout (bytes) ----------------
constexpr size_t A_OFF = 0;                      // Region A: I0 -> I2 -> {I4, feat, rp512}
constexpr size_t B_OFF = 106463232;              // Region B: I1 -> I3
constexpr size_t W_OFF = 161579008;              // converted weights

constexpr int I0_E = 32 * 114 * 114 * 64;    // 26,615,808
constexpr int I1_E = 32 * 58 * 58 * 128;     // 13,778,944
constexpr int I2_E = 32 * 30 * 30 * 256;     //  7,372,800
constexpr int I3_E = 32 * 16 * 16 * 512;     //  4,194,304
constexpr int I4_E = 32 * 7 * 7 * 512;       //    802,816

// ---------------- weight convert: OIHW fp32 -> [tap][co][ci] fp16 hi/lo -----
__global__ __launch_bounds__(256)
void wcvt(const float* __restrict__ src, _Float16* __restrict__ dHi,
          _Float16* __restrict__ dLo, int COUT, int CIN) {
  const int total = COUT * CIN * 9;
  for (int idx = blockIdx.x * 256 + threadIdx.x; idx < total; idx += gridDim.x * 256) {
    const int co = idx / (CIN * 9);
    const int r = idx % (CIN * 9);
    const int ci = r / 9, tap = r % 9;
    const float v = src[idx];
    const _Float16 h = (_Float16)v;
    const int o = (tap * COUT + co) * CIN + ci;
    dHi[o] = h;
    dLo[o] = (_Float16)(v - (float)h);
  }
}

// ---------------- zero the 1-px pad ring of a CL fp16 buffer ----------------
__global__ __launch_bounds__(256)
void zero_ring(_Float16* __restrict__ hi, _Float16* __restrict__ lo, int P, int C) {
  const int c8n = C / 8, cells = 4 * P - 4;
  const int tot = 32 * cells * c8n;
  for (int idx = blockIdx.x * 256 + threadIdx.x; idx < tot; idx += gridDim.x * 256) {
    const int c8 = idx % c8n;
    const int cell = (idx / c8n) % cells;
    const int n = idx / (c8n * cells);
    int y, xx;
    if (cell < 2 * P) { y = (cell < P) ? 0 : (P - 1); xx = cell % P; }
    else { const int q = cell - 2 * P; y = 1 + (q >> 1); xx = (q & 1) ? (P - 1) : 0; }
    const long o = ((long)(n * P + y) * P + xx) * C + c8 * 8;
    h8 z = {};
    *reinterpret_cast<h8*>(hi + o) = z;
    *reinterpret_cast<h8*>(lo + o) = z;
  }
}

// ---------------- L0: 3->64 direct fp32 conv+pool, emit fp16 CL padded ------
__global__ __launch_bounds__(256)
void conv_l0(const float* __restrict__ x, const float* __restrict__ w0,
             const float* __restrict__ b0, _Float16* __restrict__ outHi,
             _Float16* __restrict__ outLo) {
  const int bid = blockIdx.x;
  const int tx0 = (bid % 7) * 16, ty0 = ((bid / 7) % 7) * 16, n = bid / 49;
  __shared__ float sIn[3 * 34 * 34];
  __shared__ float sW[1728];
  __shared__ float sB[64];
  const int tid = threadIdx.x;
  for (int idx = tid; idx < 3 * 34 * 34; idx += 256) {
    const int ci = idx / 1156, rem = idx % 1156, r = rem / 34, cc = rem % 34;
    const int y = 2 * ty0 - 1 + r, xx = 2 * tx0 - 1 + cc;
    float v = 0.f;
    if ((unsigned)y < 224u && (unsigned)xx < 224u)
      v = x[((n * 3 + ci) * 224 + y) * 224 + xx];
    sIn[idx] = v;
  }
  for (int idx = tid; idx < 1728; idx += 256) sW[idx] = w0[idx];
  if (tid < 64) sB[tid] = b0[tid];
  __syncthreads();

  const int tpy = tid / 16, tpx = tid % 16;
  float win[3][4][4];
  #pragma unroll
  for (int ci = 0; ci < 3; ++ci)
    #pragma unroll
    for (int dr = 0; dr < 4; ++dr)
      #pragma unroll
      for (int dc = 0; dc < 4; ++dc)
        win[ci][dr][dc] = sIn[ci * 1156 + (2 * tpy + dr) * 34 + (2 * tpx + dc)];

  const long ob = ((long)(n * 114 + ty0 + tpy + 1) * 114 + tx0 + tpx + 1) * 64;
  for (int co4 = 0; co4 < 16; ++co4) {
    h4 hh, ll;
    #pragma unroll
    for (int j = 0; j < 4; ++j) {
      const int co = co4 * 4 + j;
      float a00 = 0.f, a01 = 0.f, a10 = 0.f, a11 = 0.f;
      #pragma unroll
      for (int ci = 0; ci < 3; ++ci)
        #pragma unroll
        for (int ky = 0; ky < 3; ++ky)
          #pragma unroll
          for (int kx = 0; kx < 3; ++kx) {
            const float wv = sW[co * 27 + ci * 9 + ky * 3 + kx];
            a00 = fmaf(win[ci][ky][kx], wv, a00);
            a01 = fmaf(win[ci][ky][kx + 1], wv, a01);
            a10 = fmaf(win[ci][ky + 1][kx], wv, a10);
            a11 = fmaf(win[ci][ky + 1][kx + 1], wv, a11);
          }
      const float p = fmaxf(fmaxf(fmaxf(a00, a01), fmaxf(a10, a11)) + sB[co], 0.f);
      const _Float16 h = (_Float16)p;
      hh[j] = h;
      ll[j] = (_Float16)(p - (float)h);
    }
    *reinterpret_cast<h4*>(outHi + ob + co4 * 4) = hh;
    *reinterpret_cast<h4*>(outLo + ob + co4 * 4) = ll;
  }
}

// ---------------- main conv+pool implicit GEMM (split-fp16, 3-product) ------
// Wave tile co64 x sp64 (4x4 MFMA tiles, 48 MFMA / 16 loads per K32-chunk).
// Block = 4 waves = WCO (co) x WSP (sp) wave grid.
// in: CL padded [n][H+2][W+2][CIN] hi/lo. w: [9][COUT][CIN] hi/lo.
template<int CIN, int COUT, int H, int WCO, int PADOUT, int WF32>
__global__ __launch_bounds__(256)
void convpool(const _Float16* __restrict__ inHi, const _Float16* __restrict__ inLo,
              const _Float16* __restrict__ wHi, const _Float16* __restrict__ wLo,
              const float* __restrict__ bias, _Float16* __restrict__ outHi,
              _Float16* __restrict__ outLo, float* __restrict__ outF) {
  constexpr int W = H, Hp = H / 2, Wp = W / 2, PW = W + 2, POW = Wp + 2;
  constexpr int WSP = 4 / WCO;
  const int lane = threadIdx.x & 63, wv = threadIdx.x >> 6;
  const int cow = blockIdx.y * (WCO * 64) + (wv % WCO) * 64;
  const int sblk = (blockIdx.x * WSP + (wv / WCO)) * 64;
  const int c = lane & 15, kq = lane >> 4, kof = kq * 8;

  int baseB[4];
  #pragma unroll
  for (int nt = 0; nt < 4; ++nt) {
    const int s = sblk + nt * 16 + c;
    const int ry = s & 1, t = s >> 1;
    const int x = t % W, u = t / W;
    const int py = u % Hp, n = u / Hp;
    const int y = 2 * py + ry;
    baseB[nt] = ((n * (H + 2) + y) * PW + x) * CIN;
  }
  int baseA[4];
  #pragma unroll
  for (int mt = 0; mt < 4; ++mt) baseA[mt] = (cow + mt * 16 + c) * CIN;

  f4 acc[4][4] = {};
  for (int tap = 0; tap < 9; ++tap) {
    const int ky = tap / 3, kx = tap % 3;
    const int tb = (ky * PW + kx) * CIN;
    const int ta = tap * COUT * CIN;
    for (int kc = 0; kc < CIN; kc += 32) {
      h8 aH[4], aL[4], bH[4], bL[4];
      #pragma unroll
      for (int mt = 0; mt < 4; ++mt) {
        const int ao = ta + baseA[mt] + kc + kof;
        aH[mt] = *reinterpret_cast<const h8*>(wHi + ao);
        aL[mt] = *reinterpret_cast<const h8*>(wLo + ao);
      }
      #pragma unroll
      for (int nt = 0; nt < 4; ++nt) {
        const int bo = baseB[nt] + tb + kc + kof;
        bH[nt] = *reinterpret_cast<const h8*>(inHi + bo);
        bL[nt] = *reinterpret_cast<const h8*>(inLo + bo);
      }
      #pragma unroll
      for (int mt = 0; mt < 4; ++mt)
        #pragma unroll
        for (int nt = 0; nt < 4; ++nt)
          acc[mt][nt] = MFMA16(aH[mt], bH[nt], acc[mt][nt]);
      #pragma unroll
      for (int mt = 0; mt < 4; ++mt)
        #pragma unroll
        for (int nt = 0; nt < 4; ++nt)
          acc[mt][nt] = MFMA16(aH[mt], bL[nt], acc[mt][nt]);
      #pragma unroll
      for (int mt = 0; mt < 4; ++mt)
        #pragma unroll
        for (int nt = 0; nt < 4; ++nt)
          acc[mt][nt] = MFMA16(aL[mt], bH[nt], acc[mt][nt]);
    }
  }

  // epilogue: 2x2 pool across col groups of 4, bias+relu, hi/lo CL write
  const int r4 = lane >> 4;
  #pragma unroll
  for (int mt = 0; mt < 4; ++mt) {
    const int co0 = cow + mt * 16 + r4 * 4;
    const f4 bi = *reinterpret_cast<const f4*>(bias + co0);
    #pragma unroll
    for (int nt = 0; nt < 4; ++nt) {
      f4 v = acc[mt][nt];
      #pragma unroll
      for (int r = 0; r < 4; ++r) {
        const float m1 = fmaxf(v[r], __shfl_xor(v[r], 1, 64));
        v[r] = fmaxf(m1, __shfl_xor(m1, 2, 64));
      }
      if ((lane & 3) == 0) {
        const int s = sblk + nt * 16 + c;
        const int ps = s >> 2;
        const int n = ps / (Hp * Wp), rem = ps % (Hp * Wp);
        const int py = rem / Wp, px = rem % Wp;
        h4 hh, ll;
        float fv[4];
        #pragma unroll
        for (int r = 0; r < 4; ++r) {
          const float p = fmaxf(v[r] + bi[r], 0.f);
          const _Float16 h = (_Float16)p;
          hh[r] = h;
          ll[r] = (_Float16)(p - (float)h);
          fv[r] = p;
        }
        const long oa = PADOUT
            ? ((long)((n * (Hp + 2) + py + 1) * POW + px + 1)) * COUT + co0
            : ((long)((n * Hp + py) * Wp + px)) * COUT + co0;
        *reinterpret_cast<h4*>(outHi + oa) = hh;
        *reinterpret_cast<h4*>(outLo + oa) = ll;
        if (WF32) {
          #pragma unroll
          for (int r = 0; r < 4; ++r)
            outF[((long)(n * COUT + co0 + r) * Hp + py) * Wp + px] = fv[r];
        }
      }
    }
  }
}

// ---------------- RPN: 512->512 3x3 valid on 7x7 -> 5x5, split-fp16 GEMM ----
// Output channels-last: rp512[n][pix][512]
__global__ __launch_bounds__(256)
void rpn_gemm(const _Float16* __restrict__ inHi, const _Float16* __restrict__ inLo,
              const _Float16* __restrict__ wHi, const _Float16* __restrict__ wLo,
              const float* __restrict__ bias, float* __restrict__ rp512) {
  const int lane = threadIdx.x & 63, wv = threadIdx.x >> 6;
  const int cow = blockIdx.y * 128 + wv * 32;
  const int sblk = blockIdx.x * 64;
  const int c = lane & 15, kq = lane >> 4, kof = kq * 8;

  int baseB[4];
  #pragma unroll
  for (int nt = 0; nt < 4; ++nt) {
    int s = sblk + nt * 16 + c;
    if (s > 799) s = 799;
    const int n = s / 25, pix = s % 25, py = pix / 5, px = pix % 5;
    baseB[nt] = ((n * 7 + py) * 7 + px) * 512;
  }
  const int baseA0 = (cow + c) * 512;
  const int baseA1 = (cow + 16 + c) * 512;

  f4 acc[2][4] = {};
  for (int tap = 0; tap < 9; ++tap) {
    const int ky = tap / 3, kx = tap % 3;
    const int tb = (ky * 7 + kx) * 512;
    const int ta = tap * 512 * 512;
    for (int kc = 0; kc < 512; kc += 32) {
      h8 aH[2], aL[2], bH[4], bL[4];
      const int ao0 = ta + baseA0 + kc + kof, ao1 = ta + baseA1 + kc + kof;
      aH[0] = *reinterpret_cast<const h8*>(wHi + ao0);
      aL[0] = *reinterpret_cast<const h8*>(wLo + ao0);
      aH[1] = *reinterpret_cast<const h8*>(wHi + ao1);
      aL[1] = *reinterpret_cast<const h8*>(wLo + ao1);
      #pragma unroll
      for (int nt = 0; nt < 4; ++nt) {
        const int bo = baseB[nt] + tb + kc + kof;
        bH[nt] = *reinterpret_cast<const h8*>(inHi + bo);
        bL[nt] = *reinterpret_cast<const h8*>(inLo + bo);
      }
      #pragma unroll
      for (int mt = 0; mt < 2; ++mt)
        #pragma unroll
        for (int nt = 0; nt < 4; ++nt)
          acc[mt][nt] = MFMA16(aH[mt], bH[nt], acc[mt][nt]);
      #pragma unroll
      for (int mt = 0; mt < 2; ++mt)
        #pragma unroll
        for (int nt = 0; nt < 4; ++nt)
          acc[mt][nt] = MFMA16(aH[mt], bL[nt], acc[mt][nt]);
      #pragma unroll
      for (int mt = 0; mt < 2; ++mt)
        #pragma unroll
        for (int nt = 0; nt < 4; ++nt)
          acc[mt][nt] = MFMA16(aL[mt], bH[nt], acc[mt][nt]);
    }
  }

  const int r4 = lane >> 4;
  #pragma unroll
  for (int mt = 0; mt < 2; ++mt) {
    const int co0 = cow + mt * 16 + r4 * 4;
    const f4 bi = *reinterpret_cast<const f4*>(bias + co0);
    #pragma unroll
    for (int nt = 0; nt < 4; ++nt) {
      const int s = sblk + nt * 16 + c;
      if (s < 800) {
        const int n = s / 25, pix = s % 25;
        #pragma unroll
        for (int r = 0; r < 4; ++r)
          rp512[((long)(n * 25 + pix)) * 512 + co0 + r] =
              fmaxf(acc[mt][nt][r] + bi[r], 0.f);
      }
    }
  }
}

// ---------------- 1x1 heads (fp32, CL input), straight to d_out --------------
__global__ __launch_bounds__(256)
void heads_kernel(const float* __restrict__ rp512,
                  const float* __restrict__ cls_w, const float* __restrict__ cls_b,
                  const float* __restrict__ reg_w, const float* __restrict__ reg_b,
                  float* __restrict__ out) {
  const int idx = blockIdx.x * 256 + threadIdx.x;
  if (idx >= 32 * 25 * 15) return;
  const int o = idx % 15, pix = (idx / 15) % 25, n = idx / 375;
  const float* __restrict__ ip = rp512 + ((long)(n * 25 + pix)) * 512;
  const float* __restrict__ wvp = (o < 3) ? (cls_w + o * 512) : (reg_w + (o - 3) * 512);
  float acc = 0.f;
  for (int k = 0; k < 512; k += 4) {
    const f4 a = *reinterpret_cast<const f4*>(ip + k);
    const f4 b = *reinterpret_cast<const f4*>(wvp + k);
    acc = fmaf(a[0], b[0], acc); acc = fmaf(a[1], b[1], acc);
    acc = fmaf(a[2], b[2], acc); acc = fmaf(a[3], b[3], acc);
  }
  if (o < 3) {
    acc += cls_b[o];
    out[OFF_CLS + n * 75 + o * 25 + pix] = 1.f / (1.f + expf(-acc));
  } else {
    acc += reg_b[o - 3];
    out[OFF_REG + n * 300 + (o - 3) * 25 + pix] = acc;
  }
}

// ---------------- FC: grid (32,20), float4 + wave reduce ---------------------
__global__ __launch_bounds__(256)
void fc_kernel(const float* __restrict__ feat, const float* __restrict__ fw,
               const float* __restrict__ fb, float* __restrict__ out) {
  const int n = blockIdx.x, j = blockIdx.y;
  const float* __restrict__ ip = feat + (long)n * 25088;
  const float* __restrict__ wj = fw + (long)j * 25088;
  float acc = 0.f;
  for (int k = threadIdx.x * 4; k < 25088; k += 1024) {
    const f4 a = *reinterpret_cast<const f4*>(ip + k);
    const f4 b = *reinterpret_cast<const f4*>(wj + k);
    acc = fmaf(a[0], b[0], acc); acc = fmaf(a[1], b[1], acc);
    acc = fmaf(a[2], b[2], acc); acc = fmaf(a[3], b[3], acc);
  }
  #pragma unroll
  for (int m = 32; m >= 1; m >>= 1) acc += __shfl_xor(acc, m, 64);
  __shared__ float red[4];
  const int wv = threadIdx.x >> 6;
  if ((threadIdx.x & 63) == 0) red[wv] = acc;
  __syncthreads();
  if (threadIdx.x == 0)
    out[OFF_LOGITS + n * 20 + j] = red[0] + red[1] + red[2] + red[3] + fb[j];
}

// ---------------- deparam bboxes + faithful buggy-IoU greedy NMS -------------
__global__ __launch_bounds__(128)
void bbox_nms_kernel(float* __restrict__ out) {
  const int n = blockIdx.x;
  const int t = threadIdx.x;
  __shared__ float bx0[75], by0[75], bx1[75], by1[75], area[75], sc[75];
  __shared__ int rank_s[75], order_s[75], keep_s[75];

  if (t < 75) {
    const int g1 = t / 15, g2 = (t / 3) % 5, a = t % 3;
    const float aw = (a == 0) ? 56.f : (a == 1 ? 112.f : 224.f);
    const float r0 = out[OFF_REG + n * 300 + 4 * t + 0];
    const float r1 = out[OFF_REG + n * 300 + 4 * t + 1];
    const float r2 = out[OFF_REG + n * 300 + 4 * t + 2];
    const float r3 = out[OFF_REG + n * 300 + 4 * t + 3];
    const float cx = r0 * aw + (float)g1;
    const float cy = r1 * aw + (float)g2;
    const float w_ = expf(r2) * aw;
    const float h_ = expf(r3) * aw;
    const float x0 = cx - 0.5f * w_, y0 = cy - 0.5f * h_;
    const float x1 = cx + 0.5f * w_, y1 = cy + 0.5f * h_;
    bx0[t] = x0; by0[t] = y0; bx1[t] = x1; by1[t] = y1;
    area[t] = (x1 - x0 + 1.f) * (y1 - y0 + 1.f);
    out[OFF_BOXES + n * 300 + 4 * t + 0] = x0;
    out[OFF_BOXES + n * 300 + 4 * t + 1] = y0;
    out[OFF_BOXES + n * 300 + 4 * t + 2] = x1;
    out[OFF_BOXES + n * 300 + 4 * t + 3] = y1;
    sc[t] = out[OFF_CLS + n * 75 + t];
    keep_s[t] = 1;
  }
  __syncthreads();
  if (t < 75) {
    const float si = sc[t];
    int rk = 0;
    for (int j = 0; j < 75; ++j) {
      const float sj = sc[j];
      rk += (sj > si) || (sj == si && j < t);
    }
    rank_s[t] = rk;
    order_s[rk] = t;
  }
  __syncthreads();
  for (int i = 0; i < 74; ++i) {
    if (keep_s[i]) {
      const int bi = order_s[i];
      if (t > i && t < 75) {
        const int bj = order_s[t];
        const float xA = fmaxf(bx0[bi], bx0[bj]);
        const float yA = fmaxf(by0[bi], by0[bj]);
        const float xB = fminf(bx1[bi], bx1[bj]);
        const float yB = fminf(by1[bi], by1[bj]);
        const float inter = fmaxf(0.f, xB - xA + 1.f) * fmaxf(0.f, yB - yA + 1.f);
        const float iou = inter / area[bi] + area[bj] - inter;  // faithful bug
        if (iou > 0.7f) keep_s[t] = 0;
      }
    }
    __syncthreads();
  }
  if (t < 75) out[OFF_KEEP + n * 75 + t] = keep_s[rank_s[t]] ? 1.f : 0.f;
}

// ------------------------------- launch --------------------------------------
extern "C" void kernel_launch(void* const* d_in, const int* in_sizes, int n_in,
                              void* d_out, int out_size, void* d_ws, size_t ws_size,
                              hipStream_t stream) {
  (void)in_sizes; (void)n_in; (void)out_size; (void)ws_size;
  const float* x     = (const float*)d_in[0];
  const float* fw0   = (const float*)d_in[1];
  const float* fb0   = (const float*)d_in[2];
  const float* fw1   = (const float*)d_in[3];
  const float* fb1   = (const float*)d_in[4];
  const float* fw2   = (const float*)d_in[5];
  const float* fb2   = (const float*)d_in[6];
  const float* fw3   = (const float*)d_in[7];
  const float* fb3   = (const float*)d_in[8];
  const float* fw4   = (const float*)d_in[9];
  const float* fb4   = (const float*)d_in[10];
  const float* rpw_w = (const float*)d_in[11];
  const float* rpw_b = (const float*)d_in[12];
  const float* cls_w = (const float*)d_in[13];
  const float* cls_b = (const float*)d_in[14];
  const float* reg_w = (const float*)d_in[15];
  const float* reg_b = (const float*)d_in[16];
  const float* fc_w  = (const float*)d_in[17];
  const float* fc_b  = (const float*)d_in[18];
  float* out = (float*)d_out;
  char* ws = (char*)d_ws;

  // activation buffers (fp16 hi/lo planes)
  _Float16* I0h = (_Float16*)(ws + A_OFF);
  _Float16* I0l = I0h + I0_E;
  _Float16* I1h = (_Float16*)(ws + B_OFF);
  _Float16* I1l = I1h + I1_E;
  _Float16* I2h = (_Float16*)(ws + A_OFF);
  _Float16* I2l = I2h + I2_E;
  _Float16* I3h = (_Float16*)(ws + B_OFF);
  _Float16* I3l = I3h + I3_E;
  _Float16* I4h = (_Float16*)(ws + A_OFF);
  _Float16* I4l = I4h + I4_E;
  float* feat  = (float*)(ws + A_OFF + (size_t)I4_E * 4);            // after I4 hi+lo
  float* rp512 = (float*)(ws + A_OFF + (size_t)I4_E * 4 + 3211264);  // after feat

  // converted weights [tap][co][ci] hi/lo
  _Float16* w1h = (_Float16*)(ws + W_OFF);                _Float16* w1l = w1h + 73728;
  _Float16* w2h = (_Float16*)(ws + W_OFF + 294912);       _Float16* w2l = w2h + 294912;
  _Float16* w3h = (_Float16*)(ws + W_OFF + 1474560);      _Float16* w3l = w3h + 1179648;
  _Float16* w4h = (_Float16*)(ws + W_OFF + 6193152);      _Float16* w4l = w4h + 2359296;
  _Float16* wrh = (_Float16*)(ws + W_OFF + 15630336);     _Float16* wrl = wrh + 2359296;

  // weight conversion
  wcvt<<<(73728 + 255) / 256, 256, 0, stream>>>(fw1, w1h, w1l, 128, 64);
  wcvt<<<(294912 + 255) / 256, 256, 0, stream>>>(fw2, w2h, w2l, 256, 128);
  wcvt<<<(1179648 + 255) / 256, 256, 0, stream>>>(fw3, w3h, w3l, 512, 256);
  wcvt<<<(2359296 + 255) / 256, 256, 0, stream>>>(fw4, w4h, w4l, 512, 512);
  wcvt<<<(2359296 + 255) / 256, 256, 0, stream>>>(rpw_w, wrh, wrl, 512, 512);

  // pad rings for I0, I1 (regions free now)
  zero_ring<<<512, 256, 0, stream>>>(I0h, I0l, 114, 64);
  zero_ring<<<512, 256, 0, stream>>>(I1h, I1l, 58, 128);

  // L0 direct conv
  conv_l0<<<32 * 49, 256, 0, stream>>>(x, fw0, fb0, I0h, I0l);

  // L1: 64->128 @112 (WCO=2: block co128 x sp128)
  convpool<64, 128, 112, 2, 1, 0><<<dim3(3136, 1), 256, 0, stream>>>(
      I0h, I0l, w1h, w1l, fb1, I1h, I1l, nullptr);
  zero_ring<<<512, 256, 0, stream>>>(I2h, I2l, 30, 256);   // I0 region now free
  // L2: 128->256 @56 (WCO=4: block co256 x sp64)
  convpool<128, 256, 56, 4, 1, 0><<<dim3(1568, 1), 256, 0, stream>>>(
      I1h, I1l, w2h, w2l, fb2, I2h, I2l, nullptr);
  zero_ring<<<512, 256, 0, stream>>>(I3h, I3l, 16, 512);   // I1 region now free
  // L3: 256->512 @28
  convpool<256, 512, 28, 4, 1, 0><<<dim3(392, 2), 256, 0, stream>>>(
      I2h, I2l, w3h, w3l, fb3, I3h, I3l, nullptr);
  // L4: 512->512 @14 ; writes I4 (tight CL) + feat (fp32 NCHW)
  convpool<512, 512, 14, 4, 0, 1><<<dim3(98, 2), 256, 0, stream>>>(
      I3h, I3l, w4h, w4l, fb4, I4h, I4l, feat);

  // RPN + heads + fc + nms
  rpn_gemm<<<dim3(13, 4), 256, 0, stream>>>(I4h, I4l, wrh, wrl, rpw_b, rp512);
  heads_kernel<<<(12000 + 255) / 256, 256, 0, stream>>>(rp512, cls_w, cls_b, reg_w, reg_b, out);
  fc_kernel<<<dim3(32, 20), 256, 0, stream>>>(feat, fc_w, fc_b, out);
  bbox_nms_kernel<<<BATCH, 128, 0, stream>>>(out);
}

// Round 4
// 1059.980 us; speedup vs baseline: 22.5090x; 2.0999x over previous
//
#include <hip/hip_runtime.h>
#include <math.h>

// VGG_RP round 4: LDS-pipelined split-fp16 MFMA conv.
//  - weights re-laid out [tap*kchunk][co][32] -> dense 1KB coalesced A loads
//  - B tile staged in LDS via global_load_lds (swizzled source, m97-style
//    double-buffer, one barrier per K-chunk), shared by all waves in block
//  - L4 split-tap x3 + l4_finish; RPN split-tap x9 + rpn_finish (parallelism)
// heads/fc/nms/L0 unchanged from passing rounds.
//
// d_out (float32), out_size = 24640:
//   [0,640) logits | [640,3040) rp_cls | [3040,12640) rp_reg
//   [12640,22240) bboxes | [22240,24640) keep

#define OFF_LOGITS 0
#define OFF_CLS    640
#define OFF_REG    3040
#define OFF_BOXES  12640
#define OFF_KEEP   22240

constexpr int BATCH = 32;

typedef _Float16 h8 __attribute__((ext_vector_type(8)));
typedef _Float16 h4 __attribute__((ext_vector_type(4)));
typedef float    f4 __attribute__((ext_vector_type(4)));

#define MFMA16(a, b, c) __builtin_amdgcn_mfma_f32_16x16x32_f16(a, b, c, 0, 0, 0)

#if defined(__has_builtin)
#  if __has_builtin(__builtin_amdgcn_global_load_lds)
#    define HAS_GLL 1
#  endif
#endif

// async global->LDS, 16B per lane. lbase must be wave-uniform (HW adds lane*16).
__device__ __forceinline__ void stage16(const _Float16* g, _Float16* lbase, int lane) {
#ifdef HAS_GLL
  __builtin_amdgcn_global_load_lds((const __attribute__((address_space(1))) void*)g,
                                   (__attribute__((address_space(3))) void*)lbase,
                                   16, 0, 0);
#else
  *reinterpret_cast<h8*>(lbase + lane * 8) = *reinterpret_cast<const h8*>(g);
#endif
}

// ---------------- workspace layout (bytes) ----------------
constexpr size_t A_OFF = 0;              // I0 -> I2 -> {I4, feat, rp512, partials}
constexpr size_t B_OFF = 106463232;      // I1 -> I3
constexpr size_t W_OFF = 161579008;      // converted weights
constexpr size_t P_OFF = A_OFF + 8388608;  // partials (overlay dead I2, after I4/feat/rp512)

constexpr int I0_E = 26615808;   // 32*114*114*64
constexpr int I1_E = 13778944;   // 32*58*58*128
constexpr int I2_E = 7372800;    // 32*30*30*256
constexpr int I3_E = 4194304;    // 32*16*16*512
constexpr int I4_E = 802816;     // 32*7*7*512

// ---------------- weight convert: OIHW fp32 -> [tap*kch][co][32] hi/lo ------
__global__ __launch_bounds__(256)
void wcvt(const float* __restrict__ src, _Float16* __restrict__ dHi,
          _Float16* __restrict__ dLo, int COUT, int CIN) {
  const int total = COUT * CIN * 9;
  for (int idx = blockIdx.x * 256 + threadIdx.x; idx < total; idx += gridDim.x * 256) {
    const int co = idx / (CIN * 9);
    const int r = idx % (CIN * 9);
    const int ci = r / 9, tap = r % 9;
    const float v = src[idx];
    const _Float16 h = (_Float16)v;
    const int o = ((tap * (CIN >> 5) + (ci >> 5)) * COUT + co) * 32 + (ci & 31);
    dHi[o] = h;
    dLo[o] = (_Float16)(v - (float)h);
  }
}

// ---------------- zero the 1-px pad ring of a CL fp16 buffer ----------------
__global__ __launch_bounds__(256)
void zero_ring(_Float16* __restrict__ hi, _Float16* __restrict__ lo, int P, int C) {
  const int c8n = C / 8, cells = 4 * P - 4;
  const int tot = 32 * cells * c8n;
  for (int idx = blockIdx.x * 256 + threadIdx.x; idx < tot; idx += gridDim.x * 256) {
    const int c8 = idx % c8n;
    const int cell = (idx / c8n) % cells;
    const int n = idx / (c8n * cells);
    int y, xx;
    if (cell < 2 * P) { y = (cell < P) ? 0 : (P - 1); xx = cell % P; }
    else { const int q = cell - 2 * P; y = 1 + (q >> 1); xx = (q & 1) ? (P - 1) : 0; }
    const long o = ((long)(n * P + y) * P + xx) * C + c8 * 8;
    h8 z = {};
    *reinterpret_cast<h8*>(hi + o) = z;
    *reinterpret_cast<h8*>(lo + o) = z;
  }
}

// ---------------- L0: 3->64 direct fp32 conv+pool, emit fp16 CL padded ------
__global__ __launch_bounds__(256)
void conv_l0(const float* __restrict__ x, const float* __restrict__ w0,
             const float* __restrict__ b0, _Float16* __restrict__ outHi,
             _Float16* __restrict__ outLo) {
  const int bid = blockIdx.x;
  const int tx0 = (bid % 7) * 16, ty0 = ((bid / 7) % 7) * 16, n = bid / 49;
  __shared__ float sIn[3 * 34 * 34];
  __shared__ float sW[1728];
  __shared__ float sB[64];
  const int tid = threadIdx.x;
  for (int idx = tid; idx < 3 * 34 * 34; idx += 256) {
    const int ci = idx / 1156, rem = idx % 1156, r = rem / 34, cc = rem % 34;
    const int y = 2 * ty0 - 1 + r, xx = 2 * tx0 - 1 + cc;
    float v = 0.f;
    if ((unsigned)y < 224u && (unsigned)xx < 224u)
      v = x[((n * 3 + ci) * 224 + y) * 224 + xx];
    sIn[idx] = v;
  }
  for (int idx = tid; idx < 1728; idx += 256) sW[idx] = w0[idx];
  if (tid < 64) sB[tid] = b0[tid];
  __syncthreads();

  const int tpy = tid / 16, tpx = tid % 16;
  float win[3][4][4];
  #pragma unroll
  for (int ci = 0; ci < 3; ++ci)
    #pragma unroll
    for (int dr = 0; dr < 4; ++dr)
      #pragma unroll
      for (int dc = 0; dc < 4; ++dc)
        win[ci][dr][dc] = sIn[ci * 1156 + (2 * tpy + dr) * 34 + (2 * tpx + dc)];

  const long ob = ((long)(n * 114 + ty0 + tpy + 1) * 114 + tx0 + tpx + 1) * 64;
  for (int co4 = 0; co4 < 16; ++co4) {
    h4 hh, ll;
    #pragma unroll
    for (int j = 0; j < 4; ++j) {
      const int co = co4 * 4 + j;
      float a00 = 0.f, a01 = 0.f, a10 = 0.f, a11 = 0.f;
      #pragma unroll
      for (int ci = 0; ci < 3; ++ci)
        #pragma unroll
        for (int ky = 0; ky < 3; ++ky)
          #pragma unroll
          for (int kx = 0; kx < 3; ++kx) {
            const float wv = sW[co * 27 + ci * 9 + ky * 3 + kx];
            a00 = fmaf(win[ci][ky][kx], wv, a00);
            a01 = fmaf(win[ci][ky][kx + 1], wv, a01);
            a10 = fmaf(win[ci][ky + 1][kx], wv, a10);
            a11 = fmaf(win[ci][ky + 1][kx + 1], wv, a11);
          }
      const float p = fmaxf(fmaxf(fmaxf(a00, a01), fmaxf(a10, a11)) + sB[co], 0.f);
      const _Float16 h = (_Float16)p;
      hh[j] = h;
      ll[j] = (_Float16)(p - (float)h);
    }
    *reinterpret_cast<h4*>(outHi + ob + co4 * 4) = hh;
    *reinterpret_cast<h4*>(outLo + ob + co4 * 4) = ll;
  }
}

// ---------------- main conv(+pool) implicit GEMM, LDS-pipelined -------------
// Block: NCOW x NSPW waves of 64 (=4 waves). B tile [BSP][32] hi/lo staged in
// LDS (double-buffered, XOR-slot swizzle); A loads dense 1KB from chunked
// weight layout. MODE 0: fused pool/bias/relu epilogue (TG==9).
// MODE 1: fp32 partial write (split-tap, TG taps starting at blockIdx.z*TG).
template<int CIN, int COUT, int H, int BCO, int BSP, int TG, int MODE>
__global__ __launch_bounds__(256)
void convpool(const _Float16* __restrict__ inHi, const _Float16* __restrict__ inLo,
              const _Float16* __restrict__ wHi, const _Float16* __restrict__ wLo,
              const float* __restrict__ bias, _Float16* __restrict__ outHi,
              _Float16* __restrict__ outLo, float* __restrict__ outF) {
  constexpr int W = H, Hp = H / 2, Wp = W / 2, PW = W + 2, POW = Wp + 2;
  constexpr int NCOW = BCO / 64, NSPW = BSP / 64;
  static_assert(NCOW * NSPW == 4, "4 waves");
  constexpr int KCH = CIN / 32;
  constexpr int NCH = TG * KCH;
  constexpr int NISS = BSP / 64;
  constexpr int SPTOT = 32 * H * W;
  __align__(16) __shared__ _Float16 sB[2][2][BSP * 32];

  const int tid = threadIdx.x;
  const int lane = tid & 63, wv = tid >> 6;
  const int c = lane & 15, kq = lane >> 4;
  const int cow = blockIdx.y * BCO + (wv % NCOW) * 64;
  const int spl = (wv / NCOW) * 64;
  const int sblk = blockIdx.x * BSP;
  const int tap0 = (TG == 9) ? 0 : blockIdx.z * TG;

  // per-thread staging source base (incl. swizzled k-slot), per 64-row issue
  int gstage[NISS];
  #pragma unroll
  for (int i = 0; i < NISS; ++i) {
    const int sl = i * 64 + tid / 4;
    const int sg = sblk + sl;
    const int ry = sg & 1, tt = sg >> 1;
    const int x = tt % W, u = tt / W;
    const int py = u % Hp, n = u / Hp;
    gstage[i] = ((n * (H + 2) + 2 * py + ry) * PW + x) * CIN + (((tid & 3) ^ (sl & 3)) * 8);
  }
  // ds_read element offsets (swizzled) per nt
  int dsoff[4];
  #pragma unroll
  for (int nt = 0; nt < 4; ++nt) {
    const int row = spl + nt * 16 + c;
    dsoff[nt] = row * 32 + ((kq ^ (c & 3)) * 8);
  }

  // prologue: stage chunk 0 into buf 0
  {
    const int tb = ((tap0 / 3) * PW + (tap0 % 3)) * CIN;
    #pragma unroll
    for (int i = 0; i < NISS; ++i) {
      stage16(inHi + gstage[i] + tb, &sB[0][0][i * 2048 + wv * 512], lane);
      stage16(inLo + gstage[i] + tb, &sB[0][1][i * 2048 + wv * 512], lane);
    }
  }
  __syncthreads();

  f4 acc[4][4] = {};
  int cur = 0;
  for (int ch = 0; ch < NCH; ++ch) {
    const int tap = tap0 + ch / KCH;
    const int kcI = ch % KCH;
    // A loads for current chunk (dense 1KB per instruction) — issue FIRST so
    // their waitcnt doesn't drain the stage issued below.
    h8 aH[4], aL[4];
    const long abase = ((long)(tap * KCH + kcI) * COUT + cow) * 32;
    #pragma unroll
    for (int mt = 0; mt < 4; ++mt) {
      const long ao = abase + (mt * 16 + c) * 32 + kq * 8;
      aH[mt] = *reinterpret_cast<const h8*>(wHi + ao);
      aL[mt] = *reinterpret_cast<const h8*>(wLo + ao);
    }
    // stage next chunk into the other buffer (async, drains at the barrier)
    if (ch + 1 < NCH) {
      const int tap2 = tap0 + (ch + 1) / KCH;
      const int tb2 = ((tap2 / 3) * PW + (tap2 % 3)) * CIN + ((ch + 1) % KCH) * 32;
      #pragma unroll
      for (int i = 0; i < NISS; ++i) {
        stage16(inHi + gstage[i] + tb2, &sB[cur ^ 1][0][i * 2048 + wv * 512], lane);
        stage16(inLo + gstage[i] + tb2, &sB[cur ^ 1][1][i * 2048 + wv * 512], lane);
      }
    }
    // B fragments from LDS
    h8 bH[4], bL[4];
    #pragma unroll
    for (int nt = 0; nt < 4; ++nt) {
      bH[nt] = *reinterpret_cast<const h8*>(&sB[cur][0][dsoff[nt]]);
      bL[nt] = *reinterpret_cast<const h8*>(&sB[cur][1][dsoff[nt]]);
    }
    #pragma unroll
    for (int mt = 0; mt < 4; ++mt)
      #pragma unroll
      for (int nt = 0; nt < 4; ++nt)
        acc[mt][nt] = MFMA16(aH[mt], bH[nt], acc[mt][nt]);
    #pragma unroll
    for (int mt = 0; mt < 4; ++mt)
      #pragma unroll
      for (int nt = 0; nt < 4; ++nt)
        acc[mt][nt] = MFMA16(aH[mt], bL[nt], acc[mt][nt]);
    #pragma unroll
    for (int mt = 0; mt < 4; ++mt)
      #pragma unroll
      for (int nt = 0; nt < 4; ++nt)
        acc[mt][nt] = MFMA16(aL[mt], bH[nt], acc[mt][nt]);
    __syncthreads();
    cur ^= 1;
  }

  const int r4 = lane >> 4;
  if (MODE == 1) {
    // fp32 partials, no bias/pool
    #pragma unroll
    for (int mt = 0; mt < 4; ++mt) {
      const int co0 = cow + mt * 16 + r4 * 4;
      #pragma unroll
      for (int nt = 0; nt < 4; ++nt) {
        const int s = sblk + spl + nt * 16 + c;
        *reinterpret_cast<f4*>(outF + ((long)blockIdx.z * SPTOT + s) * COUT + co0) =
            acc[mt][nt];
      }
    }
  } else {
    // fused 2x2 pool + bias + relu + hi/lo CL write
    #pragma unroll
    for (int mt = 0; mt < 4; ++mt) {
      const int co0 = cow + mt * 16 + r4 * 4;
      const f4 bi = *reinterpret_cast<const f4*>(bias + co0);
      #pragma unroll
      for (int nt = 0; nt < 4; ++nt) {
        f4 v = acc[mt][nt];
        #pragma unroll
        for (int r = 0; r < 4; ++r) {
          const float m1 = fmaxf(v[r], __shfl_xor(v[r], 1, 64));
          v[r] = fmaxf(m1, __shfl_xor(m1, 2, 64));
        }
        if ((lane & 3) == 0) {
          const int s = sblk + spl + nt * 16 + c;
          const int ps = s >> 2;
          const int n = ps / (Hp * Wp), rem = ps % (Hp * Wp);
          const int py = rem / Wp, px = rem % Wp;
          h4 hh, ll;
          #pragma unroll
          for (int r = 0; r < 4; ++r) {
            const float p = fmaxf(v[r] + bi[r], 0.f);
            const _Float16 h = (_Float16)p;
            hh[r] = h;
            ll[r] = (_Float16)(p - (float)h);
          }
          const long oa = ((long)((n * (Hp + 2) + py + 1) * POW + px + 1)) * COUT + co0;
          *reinterpret_cast<h4*>(outHi + oa) = hh;
          *reinterpret_cast<h4*>(outLo + oa) = ll;
        }
      }
    }
  }
}

// ---------------- l4_finish: sum 3 partials, pool, bias, relu ---------------
// partials [3][6272][512]; pooled p = s/4. Writes I4 CL hi/lo + feat fp32 NCHW.
__global__ __launch_bounds__(256)
void l4_finish(const float* __restrict__ part, const float* __restrict__ bias,
               _Float16* __restrict__ I4h, _Float16* __restrict__ I4l,
               float* __restrict__ feat) {
  const int t = blockIdx.x * 256 + threadIdx.x;
  if (t >= 1568 * 128) return;
  const int co0 = (t % 128) * 4, p = t / 128;
  f4 m;
  #pragma unroll
  for (int q = 0; q < 4; ++q) {
    const long s = 4L * p + q;
    f4 v = *reinterpret_cast<const f4*>(part + s * 512 + co0);
    v += *reinterpret_cast<const f4*>(part + (6272 + s) * 512 + co0);
    v += *reinterpret_cast<const f4*>(part + (12544 + s) * 512 + co0);
    if (q == 0) m = v;
    else {
      #pragma unroll
      for (int r = 0; r < 4; ++r) m[r] = fmaxf(m[r], v[r]);
    }
  }
  const f4 bi = *reinterpret_cast<const f4*>(bias + co0);
  h4 hh, ll;
  const int n = p / 49, pix = p % 49;
  #pragma unroll
  for (int r = 0; r < 4; ++r) {
    const float pv = fmaxf(m[r] + bi[r], 0.f);
    const _Float16 h = (_Float16)pv;
    hh[r] = h;
    ll[r] = (_Float16)(pv - (float)h);
    feat[((long)(n * 512 + co0 + r)) * 49 + pix] = pv;
  }
  *reinterpret_cast<h4*>(I4h + (long)p * 512 + co0) = hh;
  *reinterpret_cast<h4*>(I4l + (long)p * 512 + co0) = ll;
}

// ---------------- RPN partial: one tap per blockIdx.z, K=512 GEMM -----------
__global__ __launch_bounds__(256)
void rpn_partial(const _Float16* __restrict__ inHi, const _Float16* __restrict__ inLo,
                 const _Float16* __restrict__ wHi, const _Float16* __restrict__ wLo,
                 float* __restrict__ part) {
  const int lane = threadIdx.x & 63, wv = threadIdx.x >> 6;
  const int cow = blockIdx.y * 128 + wv * 32;
  const int sblk = blockIdx.x * 64;
  const int tap = blockIdx.z, ky = tap / 3, kx = tap % 3;
  const int c = lane & 15, kq = lane >> 4;

  int baseB[4];
  #pragma unroll
  for (int nt = 0; nt < 4; ++nt) {
    int s = sblk + nt * 16 + c;
    if (s > 799) s = 799;
    const int n = s / 25, pix = s % 25, py = pix / 5, px = pix % 5;
    baseB[nt] = ((n * 7 + py + ky) * 7 + px + kx) * 512;
  }

  f4 acc[2][4] = {};
  for (int kch = 0; kch < 16; ++kch) {
    h8 aH[2], aL[2], bH[4], bL[4];
    const long abase = ((long)(tap * 16 + kch) * 512 + cow) * 32;
    #pragma unroll
    for (int mt = 0; mt < 2; ++mt) {
      const long ao = abase + (mt * 16 + c) * 32 + kq * 8;
      aH[mt] = *reinterpret_cast<const h8*>(wHi + ao);
      aL[mt] = *reinterpret_cast<const h8*>(wLo + ao);
    }
    #pragma unroll
    for (int nt = 0; nt < 4; ++nt) {
      const int bo = baseB[nt] + kch * 32 + kq * 8;
      bH[nt] = *reinterpret_cast<const h8*>(inHi + bo);
      bL[nt] = *reinterpret_cast<const h8*>(inLo + bo);
    }
    #pragma unroll
    for (int mt = 0; mt < 2; ++mt)
      #pragma unroll
      for (int nt = 0; nt < 4; ++nt)
        acc[mt][nt] = MFMA16(aH[mt], bH[nt], acc[mt][nt]);
    #pragma unroll
    for (int mt = 0; mt < 2; ++mt)
      #pragma unroll
      for (int nt = 0; nt < 4; ++nt)
        acc[mt][nt] = MFMA16(aH[mt], bL[nt], acc[mt][nt]);
    #pragma unroll
    for (int mt = 0; mt < 2; ++mt)
      #pragma unroll
      for (int nt = 0; nt < 4; ++nt)
        acc[mt][nt] = MFMA16(aL[mt], bH[nt], acc[mt][nt]);
  }

  const int r4 = lane >> 4;
  #pragma unroll
  for (int mt = 0; mt < 2; ++mt) {
    const int co0 = cow + mt * 16 + r4 * 4;
    #pragma unroll
    for (int nt = 0; nt < 4; ++nt) {
      const int s = sblk + nt * 16 + c;
      if (s < 800)
        *reinterpret_cast<f4*>(part + ((long)tap * 800 + s) * 512 + co0) = acc[mt][nt];
    }
  }
}

// ---------------- rpn_finish: sum 9 taps + bias + relu -> rp512 CL ----------
__global__ __launch_bounds__(256)
void rpn_finish(const float* __restrict__ part, const float* __restrict__ bias,
                float* __restrict__ rp512) {
  const int t = blockIdx.x * 256 + threadIdx.x;
  if (t >= 800 * 128) return;
  const int co0 = (t % 128) * 4, s = t / 128;
  f4 acc = *reinterpret_cast<const f4*>(bias + co0);
  #pragma unroll
  for (int g = 0; g < 9; ++g)
    acc += *reinterpret_cast<const f4*>(part + ((long)g * 800 + s) * 512 + co0);
  f4 o;
  #pragma unroll
  for (int r = 0; r < 4; ++r) o[r] = fmaxf(acc[r], 0.f);
  *reinterpret_cast<f4*>(rp512 + (long)s * 512 + co0) = o;
}

// ---------------- 1x1 heads (fp32, CL input), straight to d_out --------------
__global__ __launch_bounds__(256)
void heads_kernel(const float* __restrict__ rp512,
                  const float* __restrict__ cls_w, const float* __restrict__ cls_b,
                  const float* __restrict__ reg_w, const float* __restrict__ reg_b,
                  float* __restrict__ out) {
  const int idx = blockIdx.x * 256 + threadIdx.x;
  if (idx >= 32 * 25 * 15) return;
  const int o = idx % 15, pix = (idx / 15) % 25, n = idx / 375;
  const float* __restrict__ ip = rp512 + ((long)(n * 25 + pix)) * 512;
  const float* __restrict__ wvp = (o < 3) ? (cls_w + o * 512) : (reg_w + (o - 3) * 512);
  float acc = 0.f;
  for (int k = 0; k < 512; k += 4) {
    const f4 a = *reinterpret_cast<const f4*>(ip + k);
    const f4 b = *reinterpret_cast<const f4*>(wvp + k);
    acc = fmaf(a[0], b[0], acc); acc = fmaf(a[1], b[1], acc);
    acc = fmaf(a[2], b[2], acc); acc = fmaf(a[3], b[3], acc);
  }
  if (o < 3) {
    acc += cls_b[o];
    out[OFF_CLS + n * 75 + o * 25 + pix] = 1.f / (1.f + expf(-acc));
  } else {
    acc += reg_b[o - 3];
    out[OFF_REG + n * 300 + (o - 3) * 25 + pix] = acc;
  }
}

// ---------------- FC: grid (32,20), float4 + wave reduce ---------------------
__global__ __launch_bounds__(256)
void fc_kernel(const float* __restrict__ feat, const float* __restrict__ fw,
               const float* __restrict__ fb, float* __restrict__ out) {
  const int n = blockIdx.x, j = blockIdx.y;
  const float* __restrict__ ip = feat + (long)n * 25088;
  const float* __restrict__ wj = fw + (long)j * 25088;
  float acc = 0.f;
  for (int k = threadIdx.x * 4; k < 25088; k += 1024) {
    const f4 a = *reinterpret_cast<const f4*>(ip + k);
    const f4 b = *reinterpret_cast<const f4*>(wj + k);
    acc = fmaf(a[0], b[0], acc); acc = fmaf(a[1], b[1], acc);
    acc = fmaf(a[2], b[2], acc); acc = fmaf(a[3], b[3], acc);
  }
  #pragma unroll
  for (int m = 32; m >= 1; m >>= 1) acc += __shfl_xor(acc, m, 64);
  __shared__ float red[4];
  const int wv = threadIdx.x >> 6;
  if ((threadIdx.x & 63) == 0) red[wv] = acc;
  __syncthreads();
  if (threadIdx.x == 0)
    out[OFF_LOGITS + n * 20 + j] = red[0] + red[1] + red[2] + red[3] + fb[j];
}

// ---------------- deparam bboxes + faithful buggy-IoU greedy NMS -------------
__global__ __launch_bounds__(128)
void bbox_nms_kernel(float* __restrict__ out) {
  const int n = blockIdx.x;
  const int t = threadIdx.x;
  __shared__ float bx0[75], by0[75], bx1[75], by1[75], area[75], sc[75];
  __shared__ int rank_s[75], order_s[75], keep_s[75];

  if (t < 75) {
    const int g1 = t / 15, g2 = (t / 3) % 5, a = t % 3;
    const float aw = (a == 0) ? 56.f : (a == 1 ? 112.f : 224.f);
    const float r0 = out[OFF_REG + n * 300 + 4 * t + 0];
    const float r1 = out[OFF_REG + n * 300 + 4 * t + 1];
    const float r2 = out[OFF_REG + n * 300 + 4 * t + 2];
    const float r3 = out[OFF_REG + n * 300 + 4 * t + 3];
    const float cx = r0 * aw + (float)g1;
    const float cy = r1 * aw + (float)g2;
    const float w_ = expf(r2) * aw;
    const float h_ = expf(r3) * aw;
    const float x0 = cx - 0.5f * w_, y0 = cy - 0.5f * h_;
    const float x1 = cx + 0.5f * w_, y1 = cy + 0.5f * h_;
    bx0[t] = x0; by0[t] = y0; bx1[t] = x1; by1[t] = y1;
    area[t] = (x1 - x0 + 1.f) * (y1 - y0 + 1.f);
    out[OFF_BOXES + n * 300 + 4 * t + 0] = x0;
    out[OFF_BOXES + n * 300 + 4 * t + 1] = y0;
    out[OFF_BOXES + n * 300 + 4 * t + 2] = x1;
    out[OFF_BOXES + n * 300 + 4 * t + 3] = y1;
    sc[t] = out[OFF_CLS + n * 75 + t];
    keep_s[t] = 1;
  }
  __syncthreads();
  if (t < 75) {
    const float si = sc[t];
    int rk = 0;
    for (int j = 0; j < 75; ++j) {
      const float sj = sc[j];
      rk += (sj > si) || (sj == si && j < t);
    }
    rank_s[t] = rk;
    order_s[rk] = t;
  }
  __syncthreads();
  for (int i = 0; i < 74; ++i) {
    if (keep_s[i]) {
      const int bi = order_s[i];
      if (t > i && t < 75) {
        const int bj = order_s[t];
        const float xA = fmaxf(bx0[bi], bx0[bj]);
        const float yA = fmaxf(by0[bi], by0[bj]);
        const float xB = fminf(bx1[bi], bx1[bj]);
        const float yB = fminf(by1[bi], by1[bj]);
        const float inter = fmaxf(0.f, xB - xA + 1.f) * fmaxf(0.f, yB - yA + 1.f);
        const float iou = inter / area[bi] + area[bj] - inter;  // faithful bug
        if (iou > 0.7f) keep_s[t] = 0;
      }
    }
    __syncthreads();
  }
  if (t < 75) out[OFF_KEEP + n * 75 + t] = keep_s[rank_s[t]] ? 1.f : 0.f;
}

// ------------------------------- launch --------------------------------------
extern "C" void kernel_launch(void* const* d_in, const int* in_sizes, int n_in,
                              void* d_out, int out_size, void* d_ws, size_t ws_size,
                              hipStream_t stream) {
  (void)in_sizes; (void)n_in; (void)out_size; (void)ws_size;
  const float* x     = (const float*)d_in[0];
  const float* fw0   = (const float*)d_in[1];
  const float* fb0   = (const float*)d_in[2];
  const float* fw1   = (const float*)d_in[3];
  const float* fb1   = (const float*)d_in[4];
  const float* fw2   = (const float*)d_in[5];
  const float* fb2   = (const float*)d_in[6];
  const float* fw3   = (const float*)d_in[7];
  const float* fb3   = (const float*)d_in[8];
  const float* fw4   = (const float*)d_in[9];
  const float* fb4   = (const float*)d_in[10];
  const float* rpw_w = (const float*)d_in[11];
  const float* rpw_b = (const float*)d_in[12];
  const float* cls_w = (const float*)d_in[13];
  const float* cls_b = (const float*)d_in[14];
  const float* reg_w = (const float*)d_in[15];
  const float* reg_b = (const float*)d_in[16];
  const float* fc_w  = (const float*)d_in[17];
  const float* fc_b  = (const float*)d_in[18];
  float* out = (float*)d_out;
  char* ws = (char*)d_ws;

  // activation buffers (fp16 hi/lo planes)
  _Float16* I0h = (_Float16*)(ws + A_OFF);
  _Float16* I0l = I0h + I0_E;
  _Float16* I1h = (_Float16*)(ws + B_OFF);
  _Float16* I1l = I1h + I1_E;
  _Float16* I2h = (_Float16*)(ws + A_OFF);
  _Float16* I2l = I2h + I2_E;
  _Float16* I3h = (_Float16*)(ws + B_OFF);
  _Float16* I3l = I3h + I3_E;
  _Float16* I4h = (_Float16*)(ws + A_OFF);
  _Float16* I4l = I4h + I4_E;
  float* feat  = (float*)(ws + A_OFF + (size_t)I4_E * 4);            // 3.2MB
  float* rp512 = (float*)(ws + A_OFF + (size_t)I4_E * 4 + 3211264);  // 1.6MB
  float* part  = (float*)(ws + P_OFF);                               // partials

  // converted weights [tap*kch][co][32] hi/lo
  _Float16* w1h = (_Float16*)(ws + W_OFF);                _Float16* w1l = w1h + 73728;
  _Float16* w2h = (_Float16*)(ws + W_OFF + 294912);       _Float16* w2l = w2h + 294912;
  _Float16* w3h = (_Float16*)(ws + W_OFF + 1474560);      _Float16* w3l = w3h + 1179648;
  _Float16* w4h = (_Float16*)(ws + W_OFF + 6193152);      _Float16* w4l = w4h + 2359296;
  _Float16* wrh = (_Float16*)(ws + W_OFF + 15630336);     _Float16* wrl = wrh + 2359296;

  // weight conversion
  wcvt<<<(73728 + 255) / 256, 256, 0, stream>>>(fw1, w1h, w1l, 128, 64);
  wcvt<<<(294912 + 255) / 256, 256, 0, stream>>>(fw2, w2h, w2l, 256, 128);
  wcvt<<<(1179648 + 255) / 256, 256, 0, stream>>>(fw3, w3h, w3l, 512, 256);
  wcvt<<<(2359296 + 255) / 256, 256, 0, stream>>>(fw4, w4h, w4l, 512, 512);
  wcvt<<<(2359296 + 255) / 256, 256, 0, stream>>>(rpw_w, wrh, wrl, 512, 512);

  // pad rings for I0, I1
  zero_ring<<<512, 256, 0, stream>>>(I0h, I0l, 114, 64);
  zero_ring<<<512, 256, 0, stream>>>(I1h, I1l, 58, 128);

  // L0 direct conv
  conv_l0<<<32 * 49, 256, 0, stream>>>(x, fw0, fb0, I0h, I0l);

  // L1: 64->128 @112, block co128 x sp128
  convpool<64, 128, 112, 128, 128, 9, 0><<<dim3(3136, 1, 1), 256, 0, stream>>>(
      I0h, I0l, w1h, w1l, fb1, I1h, I1l, nullptr);
  zero_ring<<<512, 256, 0, stream>>>(I2h, I2l, 30, 256);   // I0 region now free
  // L2: 128->256 @56, block co256 x sp64
  convpool<128, 256, 56, 256, 64, 9, 0><<<dim3(1568, 1, 1), 256, 0, stream>>>(
      I1h, I1l, w2h, w2l, fb2, I2h, I2l, nullptr);
  zero_ring<<<512, 256, 0, stream>>>(I3h, I3l, 16, 512);   // I1 region now free
  // L3: 256->512 @28
  convpool<256, 512, 28, 256, 64, 9, 0><<<dim3(392, 2, 1), 256, 0, stream>>>(
      I2h, I2l, w3h, w3l, fb3, I3h, I3l, nullptr);
  // L4: 512->512 @14, split-tap x3 -> partials, then finish
  convpool<512, 512, 14, 256, 64, 3, 1><<<dim3(98, 2, 3), 256, 0, stream>>>(
      I3h, I3l, w4h, w4l, nullptr, nullptr, nullptr, part);
  l4_finish<<<(1568 * 128 + 255) / 256, 256, 0, stream>>>(part, fb4, I4h, I4l, feat);

  // RPN: split-tap x9 -> partials, then finish
  rpn_partial<<<dim3(13, 4, 9), 256, 0, stream>>>(I4h, I4l, wrh, wrl, part);
  rpn_finish<<<(800 * 128 + 255) / 256, 256, 0, stream>>>(part, rpw_b, rp512);

  heads_kernel<<<(12000 + 255) / 256, 256, 0, stream>>>(rp512, cls_w, cls_b, reg_w, reg_b, out);
  fc_kernel<<<dim3(32, 20), 256, 0, stream>>>(feat, fc_w, fc_b, out);
  bbox_nms_kernel<<<BATCH, 128, 0, stream>>>(out);
}

// Round 5
// 1017.079 us; speedup vs baseline: 23.4584x; 1.0422x over previous
//
#include <hip/hip_runtime.h>
#include <math.h>

// VGG_RP round 5: convpool fixes from r4 counters:
//  - LDS swizzle corrected: slot = kq ^ ((row>>1)&3) on read, inverse on the
//    pre-swizzled global staging source (was (c&3): 4-way bank conflicts,
//    SQ_LDS_BANK_CONFLICT=7.2M on L3)
//  - KPH=2: stage K=64 per phase for L2/L3/L4 -> one barrier (vmcnt drain)
//    per 96 MFMAs instead of 48
// Everything else as round 4 (passed, absmax 2.4e-4).
//
// d_out (float32), out_size = 24640:
//   [0,640) logits | [640,3040) rp_cls | [3040,12640) rp_reg
//   [12640,22240) bboxes | [22240,24640) keep

#define OFF_LOGITS 0
#define OFF_CLS    640
#define OFF_REG    3040
#define OFF_BOXES  12640
#define OFF_KEEP   22240

constexpr int BATCH = 32;

typedef _Float16 h8 __attribute__((ext_vector_type(8)));
typedef _Float16 h4 __attribute__((ext_vector_type(4)));
typedef float    f4 __attribute__((ext_vector_type(4)));

#define MFMA16(a, b, c) __builtin_amdgcn_mfma_f32_16x16x32_f16(a, b, c, 0, 0, 0)

#if defined(__has_builtin)
#  if __has_builtin(__builtin_amdgcn_global_load_lds)
#    define HAS_GLL 1
#  endif
#endif

// async global->LDS, 16B per lane. lbase must be wave-uniform (HW adds lane*16).
__device__ __forceinline__ void stage16(const _Float16* g, _Float16* lbase, int lane) {
#ifdef HAS_GLL
  __builtin_amdgcn_global_load_lds((const __attribute__((address_space(1))) void*)g,
                                   (__attribute__((address_space(3))) void*)lbase,
                                   16, 0, 0);
#else
  *reinterpret_cast<h8*>(lbase + lane * 8) = *reinterpret_cast<const h8*>(g);
#endif
}

// ---------------- workspace layout (bytes) ----------------
constexpr size_t A_OFF = 0;              // I0 -> I2 -> {I4, feat, rp512, partials}
constexpr size_t B_OFF = 106463232;      // I1 -> I3
constexpr size_t W_OFF = 161579008;      // converted weights
constexpr size_t P_OFF = A_OFF + 8388608;  // partials (overlay dead I2 region)

constexpr int I0_E = 26615808;   // 32*114*114*64
constexpr int I1_E = 13778944;   // 32*58*58*128
constexpr int I2_E = 7372800;    // 32*30*30*256
constexpr int I3_E = 4194304;    // 32*16*16*512
constexpr int I4_E = 802816;     // 32*7*7*512

// ---------------- weight convert: OIHW fp32 -> [tap*kch][co][32] hi/lo ------
__global__ __launch_bounds__(256)
void wcvt(const float* __restrict__ src, _Float16* __restrict__ dHi,
          _Float16* __restrict__ dLo, int COUT, int CIN) {
  const int total = COUT * CIN * 9;
  for (int idx = blockIdx.x * 256 + threadIdx.x; idx < total; idx += gridDim.x * 256) {
    const int co = idx / (CIN * 9);
    const int r = idx % (CIN * 9);
    const int ci = r / 9, tap = r % 9;
    const float v = src[idx];
    const _Float16 h = (_Float16)v;
    const int o = ((tap * (CIN >> 5) + (ci >> 5)) * COUT + co) * 32 + (ci & 31);
    dHi[o] = h;
    dLo[o] = (_Float16)(v - (float)h);
  }
}

// ---------------- zero the 1-px pad ring of a CL fp16 buffer ----------------
__global__ __launch_bounds__(256)
void zero_ring(_Float16* __restrict__ hi, _Float16* __restrict__ lo, int P, int C) {
  const int c8n = C / 8, cells = 4 * P - 4;
  const int tot = 32 * cells * c8n;
  for (int idx = blockIdx.x * 256 + threadIdx.x; idx < tot; idx += gridDim.x * 256) {
    const int c8 = idx % c8n;
    const int cell = (idx / c8n) % cells;
    const int n = idx / (c8n * cells);
    int y, xx;
    if (cell < 2 * P) { y = (cell < P) ? 0 : (P - 1); xx = cell % P; }
    else { const int q = cell - 2 * P; y = 1 + (q >> 1); xx = (q & 1) ? (P - 1) : 0; }
    const long o = ((long)(n * P + y) * P + xx) * C + c8 * 8;
    h8 z = {};
    *reinterpret_cast<h8*>(hi + o) = z;
    *reinterpret_cast<h8*>(lo + o) = z;
  }
}

// ---------------- L0: 3->64 direct fp32 conv+pool, emit fp16 CL padded ------
__global__ __launch_bounds__(256)
void conv_l0(const float* __restrict__ x, const float* __restrict__ w0,
             const float* __restrict__ b0, _Float16* __restrict__ outHi,
             _Float16* __restrict__ outLo) {
  const int bid = blockIdx.x;
  const int tx0 = (bid % 7) * 16, ty0 = ((bid / 7) % 7) * 16, n = bid / 49;
  __shared__ float sIn[3 * 34 * 34];
  __shared__ float sW[1728];
  __shared__ float sB[64];
  const int tid = threadIdx.x;
  for (int idx = tid; idx < 3 * 34 * 34; idx += 256) {
    const int ci = idx / 1156, rem = idx % 1156, r = rem / 34, cc = rem % 34;
    const int y = 2 * ty0 - 1 + r, xx = 2 * tx0 - 1 + cc;
    float v = 0.f;
    if ((unsigned)y < 224u && (unsigned)xx < 224u)
      v = x[((n * 3 + ci) * 224 + y) * 224 + xx];
    sIn[idx] = v;
  }
  for (int idx = tid; idx < 1728; idx += 256) sW[idx] = w0[idx];
  if (tid < 64) sB[tid] = b0[tid];
  __syncthreads();

  const int tpy = tid / 16, tpx = tid % 16;
  float win[3][4][4];
  #pragma unroll
  for (int ci = 0; ci < 3; ++ci)
    #pragma unroll
    for (int dr = 0; dr < 4; ++dr)
      #pragma unroll
      for (int dc = 0; dc < 4; ++dc)
        win[ci][dr][dc] = sIn[ci * 1156 + (2 * tpy + dr) * 34 + (2 * tpx + dc)];

  const long ob = ((long)(n * 114 + ty0 + tpy + 1) * 114 + tx0 + tpx + 1) * 64;
  for (int co4 = 0; co4 < 16; ++co4) {
    h4 hh, ll;
    #pragma unroll
    for (int j = 0; j < 4; ++j) {
      const int co = co4 * 4 + j;
      float a00 = 0.f, a01 = 0.f, a10 = 0.f, a11 = 0.f;
      #pragma unroll
      for (int ci = 0; ci < 3; ++ci)
        #pragma unroll
        for (int ky = 0; ky < 3; ++ky)
          #pragma unroll
          for (int kx = 0; kx < 3; ++kx) {
            const float wv = sW[co * 27 + ci * 9 + ky * 3 + kx];
            a00 = fmaf(win[ci][ky][kx], wv, a00);
            a01 = fmaf(win[ci][ky][kx + 1], wv, a01);
            a10 = fmaf(win[ci][ky + 1][kx], wv, a10);
            a11 = fmaf(win[ci][ky + 1][kx + 1], wv, a11);
          }
      const float p = fmaxf(fmaxf(fmaxf(a00, a01), fmaxf(a10, a11)) + sB[co], 0.f);
      const _Float16 h = (_Float16)p;
      hh[j] = h;
      ll[j] = (_Float16)(p - (float)h);
    }
    *reinterpret_cast<h4*>(outHi + ob + co4 * 4) = hh;
    *reinterpret_cast<h4*>(outLo + ob + co4 * 4) = ll;
  }
}

// ---------------- main conv(+pool) implicit GEMM, LDS-pipelined -------------
// Block: 4 waves (NCOW x NSPW). B tile [BSP][32] per k-chunk, KPH chunks per
// phase, double-buffered in LDS via global_load_lds.
// Swizzle (both sides, rule #21): LDS slot s of row r holds global 16B-slot
// s ^ ((r>>1)&3); read uses s = kq ^ ((row>>1)&3) -> conflict-free quarter-wave.
// MODE 0: fused pool/bias/relu epilogue. MODE 1: fp32 partials (split-tap).
template<int CIN, int COUT, int H, int BCO, int BSP, int TG, int KPH, int MODE>
__global__ __launch_bounds__(256)
void convpool(const _Float16* __restrict__ inHi, const _Float16* __restrict__ inLo,
              const _Float16* __restrict__ wHi, const _Float16* __restrict__ wLo,
              const float* __restrict__ bias, _Float16* __restrict__ outHi,
              _Float16* __restrict__ outLo, float* __restrict__ outF) {
  constexpr int W = H, Hp = H / 2, Wp = W / 2, PW = W + 2, POW = Wp + 2;
  constexpr int NCOW = BCO / 64, NSPW = BSP / 64;
  static_assert(NCOW * NSPW == 4, "4 waves");
  constexpr int KCH = CIN / 32;
  constexpr int NCH = TG * KCH;
  constexpr int NPH = NCH / KPH;
  static_assert(NCH % KPH == 0, "even phases");
  constexpr int NISS = BSP / 64;
  constexpr int SPTOT = 32 * H * W;
  constexpr int TSZ = BSP * 32;  // elements per (hl, j) tile
  __align__(16) __shared__ _Float16 sB[2 * 2 * KPH * TSZ];
  // tile base: ((buf*2 + hl)*KPH + j) * TSZ
  #define TIDX(buf, hl, j) ((((buf) * 2 + (hl)) * KPH + (j)) * TSZ)

  const int tid = threadIdx.x;
  const int lane = tid & 63, wv = tid >> 6;
  const int c = lane & 15, kq = lane >> 4;
  const int cow = blockIdx.y * BCO + (wv % NCOW) * 64;
  const int spl = (wv / NCOW) * 64;
  const int sblk = blockIdx.x * BSP;
  const int tap0 = (TG == 9) ? 0 : blockIdx.z * TG;

  // staging source base incl. inverse-swizzled 16B slot (thread stages row
  // sl = i*64 + tid/4, local slot tid&3 -> global slot (tid&3)^((sl>>1)&3))
  int gstage[NISS];
  #pragma unroll
  for (int i = 0; i < NISS; ++i) {
    const int sl = i * 64 + tid / 4;
    const int sg = sblk + sl;
    const int ry = sg & 1, tt = sg >> 1;
    const int x = tt % W, u = tt / W;
    const int py = u % Hp, n = u / Hp;
    gstage[i] = ((n * (H + 2) + 2 * py + ry) * PW + x) * CIN +
                (((tid & 3) ^ ((sl >> 1) & 3)) * 8);
  }
  // ds_read offsets (swizzled) per nt
  int dsoff[4];
  #pragma unroll
  for (int nt = 0; nt < 4; ++nt) {
    const int row = spl + nt * 16 + c;
    dsoff[nt] = row * 32 + ((kq ^ ((row >> 1) & 3)) * 8);
  }

  // prologue: stage phase 0 (KPH chunks) into buf 0
  #pragma unroll
  for (int j = 0; j < KPH; ++j) {
    const int tap = tap0 + j / KCH, kc = j % KCH;
    const int tb = ((tap / 3) * PW + (tap % 3)) * CIN + kc * 32;
    #pragma unroll
    for (int i = 0; i < NISS; ++i) {
      stage16(inHi + gstage[i] + tb, &sB[TIDX(0, 0, j) + i * 2048 + wv * 512], lane);
      stage16(inLo + gstage[i] + tb, &sB[TIDX(0, 1, j) + i * 2048 + wv * 512], lane);
    }
  }
  __syncthreads();

  f4 acc[4][4] = {};
  int cur = 0;
  for (int ph = 0; ph < NPH; ++ph) {
    #pragma unroll
    for (int j = 0; j < KPH; ++j) {
      const int ch = ph * KPH + j;
      const int tap = tap0 + ch / KCH;
      const int kc = ch % KCH;
      // A loads (dense 1KB per instruction) — issued before this sub-chunk's
      // staging so their waitcnt doesn't drain the stage queue.
      h8 aH[4], aL[4];
      const long abase = ((long)(tap * KCH + kc) * COUT + cow) * 32;
      #pragma unroll
      for (int mt = 0; mt < 4; ++mt) {
        const long ao = abase + (mt * 16 + c) * 32 + kq * 8;
        aH[mt] = *reinterpret_cast<const h8*>(wHi + ao);
        aL[mt] = *reinterpret_cast<const h8*>(wLo + ao);
      }
      // stage next phase (once per phase, after first A-load batch)
      if (j == 0 && ph + 1 < NPH) {
        #pragma unroll
        for (int j2 = 0; j2 < KPH; ++j2) {
          const int ch2 = (ph + 1) * KPH + j2;
          const int tap2 = tap0 + ch2 / KCH;
          const int tb2 = ((tap2 / 3) * PW + (tap2 % 3)) * CIN + (ch2 % KCH) * 32;
          #pragma unroll
          for (int i = 0; i < NISS; ++i) {
            stage16(inHi + gstage[i] + tb2,
                    &sB[TIDX(cur ^ 1, 0, j2) + i * 2048 + wv * 512], lane);
            stage16(inLo + gstage[i] + tb2,
                    &sB[TIDX(cur ^ 1, 1, j2) + i * 2048 + wv * 512], lane);
          }
        }
      }
      // B fragments from LDS
      h8 bH[4], bL[4];
      #pragma unroll
      for (int nt = 0; nt < 4; ++nt) {
        bH[nt] = *reinterpret_cast<const h8*>(&sB[TIDX(cur, 0, j) + dsoff[nt]]);
        bL[nt] = *reinterpret_cast<const h8*>(&sB[TIDX(cur, 1, j) + dsoff[nt]]);
      }
      #pragma unroll
      for (int mt = 0; mt < 4; ++mt)
        #pragma unroll
        for (int nt = 0; nt < 4; ++nt)
          acc[mt][nt] = MFMA16(aH[mt], bH[nt], acc[mt][nt]);
      #pragma unroll
      for (int mt = 0; mt < 4; ++mt)
        #pragma unroll
        for (int nt = 0; nt < 4; ++nt)
          acc[mt][nt] = MFMA16(aH[mt], bL[nt], acc[mt][nt]);
      #pragma unroll
      for (int mt = 0; mt < 4; ++mt)
        #pragma unroll
        for (int nt = 0; nt < 4; ++nt)
          acc[mt][nt] = MFMA16(aL[mt], bH[nt], acc[mt][nt]);
    }
    __syncthreads();
    cur ^= 1;
  }
  #undef TIDX

  const int r4 = lane >> 4;
  if (MODE == 1) {
    // fp32 partials, no bias/pool
    #pragma unroll
    for (int mt = 0; mt < 4; ++mt) {
      const int co0 = cow + mt * 16 + r4 * 4;
      #pragma unroll
      for (int nt = 0; nt < 4; ++nt) {
        const int s = sblk + spl + nt * 16 + c;
        *reinterpret_cast<f4*>(outF + ((long)blockIdx.z * SPTOT + s) * COUT + co0) =
            acc[mt][nt];
      }
    }
  } else {
    // fused 2x2 pool + bias + relu + hi/lo CL write
    #pragma unroll
    for (int mt = 0; mt < 4; ++mt) {
      const int co0 = cow + mt * 16 + r4 * 4;
      const f4 bi = *reinterpret_cast<const f4*>(bias + co0);
      #pragma unroll
      for (int nt = 0; nt < 4; ++nt) {
        f4 v = acc[mt][nt];
        #pragma unroll
        for (int r = 0; r < 4; ++r) {
          const float m1 = fmaxf(v[r], __shfl_xor(v[r], 1, 64));
          v[r] = fmaxf(m1, __shfl_xor(m1, 2, 64));
        }
        if ((lane & 3) == 0) {
          const int s = sblk + spl + nt * 16 + c;
          const int ps = s >> 2;
          const int n = ps / (Hp * Wp), rem = ps % (Hp * Wp);
          const int py = rem / Wp, px = rem % Wp;
          h4 hh, ll;
          #pragma unroll
          for (int r = 0; r < 4; ++r) {
            const float p = fmaxf(v[r] + bi[r], 0.f);
            const _Float16 h = (_Float16)p;
            hh[r] = h;
            ll[r] = (_Float16)(p - (float)h);
          }
          const long oa = ((long)((n * (Hp + 2) + py + 1) * POW + px + 1)) * COUT + co0;
          *reinterpret_cast<h4*>(outHi + oa) = hh;
          *reinterpret_cast<h4*>(outLo + oa) = ll;
        }
      }
    }
  }
}

// ---------------- l4_finish: sum 3 partials, pool, bias, relu ---------------
__global__ __launch_bounds__(256)
void l4_finish(const float* __restrict__ part, const float* __restrict__ bias,
               _Float16* __restrict__ I4h, _Float16* __restrict__ I4l,
               float* __restrict__ feat) {
  const int t = blockIdx.x * 256 + threadIdx.x;
  if (t >= 1568 * 128) return;
  const int co0 = (t % 128) * 4, p = t / 128;
  f4 m;
  #pragma unroll
  for (int q = 0; q < 4; ++q) {
    const long s = 4L * p + q;
    f4 v = *reinterpret_cast<const f4*>(part + s * 512 + co0);
    v += *reinterpret_cast<const f4*>(part + (6272 + s) * 512 + co0);
    v += *reinterpret_cast<const f4*>(part + (12544 + s) * 512 + co0);
    if (q == 0) m = v;
    else {
      #pragma unroll
      for (int r = 0; r < 4; ++r) m[r] = fmaxf(m[r], v[r]);
    }
  }
  const f4 bi = *reinterpret_cast<const f4*>(bias + co0);
  h4 hh, ll;
  const int n = p / 49, pix = p % 49;
  #pragma unroll
  for (int r = 0; r < 4; ++r) {
    const float pv = fmaxf(m[r] + bi[r], 0.f);
    const _Float16 h = (_Float16)pv;
    hh[r] = h;
    ll[r] = (_Float16)(pv - (float)h);
    feat[((long)(n * 512 + co0 + r)) * 49 + pix] = pv;
  }
  *reinterpret_cast<h4*>(I4h + (long)p * 512 + co0) = hh;
  *reinterpret_cast<h4*>(I4l + (long)p * 512 + co0) = ll;
}

// ---------------- RPN partial: one tap per blockIdx.z, K=512 GEMM -----------
__global__ __launch_bounds__(256)
void rpn_partial(const _Float16* __restrict__ inHi, const _Float16* __restrict__ inLo,
                 const _Float16* __restrict__ wHi, const _Float16* __restrict__ wLo,
                 float* __restrict__ part) {
  const int lane = threadIdx.x & 63, wv = threadIdx.x >> 6;
  const int cow = blockIdx.y * 128 + wv * 32;
  const int sblk = blockIdx.x * 64;
  const int tap = blockIdx.z, ky = tap / 3, kx = tap % 3;
  const int c = lane & 15, kq = lane >> 4;

  int baseB[4];
  #pragma unroll
  for (int nt = 0; nt < 4; ++nt) {
    int s = sblk + nt * 16 + c;
    if (s > 799) s = 799;
    const int n = s / 25, pix = s % 25, py = pix / 5, px = pix % 5;
    baseB[nt] = ((n * 7 + py + ky) * 7 + px + kx) * 512;
  }

  f4 acc[2][4] = {};
  for (int kch = 0; kch < 16; ++kch) {
    h8 aH[2], aL[2], bH[4], bL[4];
    const long abase = ((long)(tap * 16 + kch) * 512 + cow) * 32;
    #pragma unroll
    for (int mt = 0; mt < 2; ++mt) {
      const long ao = abase + (mt * 16 + c) * 32 + kq * 8;
      aH[mt] = *reinterpret_cast<const h8*>(wHi + ao);
      aL[mt] = *reinterpret_cast<const h8*>(wLo + ao);
    }
    #pragma unroll
    for (int nt = 0; nt < 4; ++nt) {
      const int bo = baseB[nt] + kch * 32 + kq * 8;
      bH[nt] = *reinterpret_cast<const h8*>(inHi + bo);
      bL[nt] = *reinterpret_cast<const h8*>(inLo + bo);
    }
    #pragma unroll
    for (int mt = 0; mt < 2; ++mt)
      #pragma unroll
      for (int nt = 0; nt < 4; ++nt)
        acc[mt][nt] = MFMA16(aH[mt], bH[nt], acc[mt][nt]);
    #pragma unroll
    for (int mt = 0; mt < 2; ++mt)
      #pragma unroll
      for (int nt = 0; nt < 4; ++nt)
        acc[mt][nt] = MFMA16(aH[mt], bL[nt], acc[mt][nt]);
    #pragma unroll
    for (int mt = 0; mt < 2; ++mt)
      #pragma unroll
      for (int nt = 0; nt < 4; ++nt)
        acc[mt][nt] = MFMA16(aL[mt], bH[nt], acc[mt][nt]);
  }

  const int r4 = lane >> 4;
  #pragma unroll
  for (int mt = 0; mt < 2; ++mt) {
    const int co0 = cow + mt * 16 + r4 * 4;
    #pragma unroll
    for (int nt = 0; nt < 4; ++nt) {
      const int s = sblk + nt * 16 + c;
      if (s < 800)
        *reinterpret_cast<f4*>(part + ((long)tap * 800 + s) * 512 + co0) = acc[mt][nt];
    }
  }
}

// ---------------- rpn_finish: sum 9 taps + bias + relu -> rp512 CL ----------
__global__ __launch_bounds__(256)
void rpn_finish(const float* __restrict__ part, const float* __restrict__ bias,
                float* __restrict__ rp512) {
  const int t = blockIdx.x * 256 + threadIdx.x;
  if (t >= 800 * 128) return;
  const int co0 = (t % 128) * 4, s = t / 128;
  f4 acc = *reinterpret_cast<const f4*>(bias + co0);
  #pragma unroll
  for (int g = 0; g < 9; ++g)
    acc += *reinterpret_cast<const f4*>(part + ((long)g * 800 + s) * 512 + co0);
  f4 o;
  #pragma unroll
  for (int r = 0; r < 4; ++r) o[r] = fmaxf(acc[r], 0.f);
  *reinterpret_cast<f4*>(rp512 + (long)s * 512 + co0) = o;
}

// ---------------- 1x1 heads (fp32, CL input), straight to d_out --------------
__global__ __launch_bounds__(256)
void heads_kernel(const float* __restrict__ rp512,
                  const float* __restrict__ cls_w, const float* __restrict__ cls_b,
                  const float* __restrict__ reg_w, const float* __restrict__ reg_b,
                  float* __restrict__ out) {
  const int idx = blockIdx.x * 256 + threadIdx.x;
  if (idx >= 32 * 25 * 15) return;
  const int o = idx % 15, pix = (idx / 15) % 25, n = idx / 375;
  const float* __restrict__ ip = rp512 + ((long)(n * 25 + pix)) * 512;
  const float* __restrict__ wvp = (o < 3) ? (cls_w + o * 512) : (reg_w + (o - 3) * 512);
  float acc = 0.f;
  for (int k = 0; k < 512; k += 4) {
    const f4 a = *reinterpret_cast<const f4*>(ip + k);
    const f4 b = *reinterpret_cast<const f4*>(wvp + k);
    acc = fmaf(a[0], b[0], acc); acc = fmaf(a[1], b[1], acc);
    acc = fmaf(a[2], b[2], acc); acc = fmaf(a[3], b[3], acc);
  }
  if (o < 3) {
    acc += cls_b[o];
    out[OFF_CLS + n * 75 + o * 25 + pix] = 1.f / (1.f + expf(-acc));
  } else {
    acc += reg_b[o - 3];
    out[OFF_REG + n * 300 + (o - 3) * 25 + pix] = acc;
  }
}

// ---------------- FC: grid (32,20), float4 + wave reduce ---------------------
__global__ __launch_bounds__(256)
void fc_kernel(const float* __restrict__ feat, const float* __restrict__ fw,
               const float* __restrict__ fb, float* __restrict__ out) {
  const int n = blockIdx.x, j = blockIdx.y;
  const float* __restrict__ ip = feat + (long)n * 25088;
  const float* __restrict__ wj = fw + (long)j * 25088;
  float acc = 0.f;
  for (int k = threadIdx.x * 4; k < 25088; k += 1024) {
    const f4 a = *reinterpret_cast<const f4*>(ip + k);
    const f4 b = *reinterpret_cast<const f4*>(wj + k);
    acc = fmaf(a[0], b[0], acc); acc = fmaf(a[1], b[1], acc);
    acc = fmaf(a[2], b[2], acc); acc = fmaf(a[3], b[3], acc);
  }
  #pragma unroll
  for (int m = 32; m >= 1; m >>= 1) acc += __shfl_xor(acc, m, 64);
  __shared__ float red[4];
  const int wv = threadIdx.x >> 6;
  if ((threadIdx.x & 63) == 0) red[wv] = acc;
  __syncthreads();
  if (threadIdx.x == 0)
    out[OFF_LOGITS + n * 20 + j] = red[0] + red[1] + red[2] + red[3] + fb[j];
}

// ---------------- deparam bboxes + faithful buggy-IoU greedy NMS -------------
__global__ __launch_bounds__(128)
void bbox_nms_kernel(float* __restrict__ out) {
  const int n = blockIdx.x;
  const int t = threadIdx.x;
  __shared__ float bx0[75], by0[75], bx1[75], by1[75], area[75], sc[75];
  __shared__ int rank_s[75], order_s[75], keep_s[75];

  if (t < 75) {
    const int g1 = t / 15, g2 = (t / 3) % 5, a = t % 3;
    const float aw = (a == 0) ? 56.f : (a == 1 ? 112.f : 224.f);
    const float r0 = out[OFF_REG + n * 300 + 4 * t + 0];
    const float r1 = out[OFF_REG + n * 300 + 4 * t + 1];
    const float r2 = out[OFF_REG + n * 300 + 4 * t + 2];
    const float r3 = out[OFF_REG + n * 300 + 4 * t + 3];
    const float cx = r0 * aw + (float)g1;
    const float cy = r1 * aw + (float)g2;
    const float w_ = expf(r2) * aw;
    const float h_ = expf(r3) * aw;
    const float x0 = cx - 0.5f * w_, y0 = cy - 0.5f * h_;
    const float x1 = cx + 0.5f * w_, y1 = cy + 0.5f * h_;
    bx0[t] = x0; by0[t] = y0; bx1[t] = x1; by1[t] = y1;
    area[t] = (x1 - x0 + 1.f) * (y1 - y0 + 1.f);
    out[OFF_BOXES + n * 300 + 4 * t + 0] = x0;
    out[OFF_BOXES + n * 300 + 4 * t + 1] = y0;
    out[OFF_BOXES + n * 300 + 4 * t + 2] = x1;
    out[OFF_BOXES + n * 300 + 4 * t + 3] = y1;
    sc[t] = out[OFF_CLS + n * 75 + t];
    keep_s[t] = 1;
  }
  __syncthreads();
  if (t < 75) {
    const float si = sc[t];
    int rk = 0;
    for (int j = 0; j < 75; ++j) {
      const float sj = sc[j];
      rk += (sj > si) || (sj == si && j < t);
    }
    rank_s[t] = rk;
    order_s[rk] = t;
  }
  __syncthreads();
  for (int i = 0; i < 74; ++i) {
    if (keep_s[i]) {
      const int bi = order_s[i];
      if (t > i && t < 75) {
        const int bj = order_s[t];
        const float xA = fmaxf(bx0[bi], bx0[bj]);
        const float yA = fmaxf(by0[bi], by0[bj]);
        const float xB = fminf(bx1[bi], bx1[bj]);
        const float yB = fminf(by1[bi], by1[bj]);
        const float inter = fmaxf(0.f, xB - xA + 1.f) * fmaxf(0.f, yB - yA + 1.f);
        const float iou = inter / area[bi] + area[bj] - inter;  // faithful bug
        if (iou > 0.7f) keep_s[t] = 0;
      }
    }
    __syncthreads();
  }
  if (t < 75) out[OFF_KEEP + n * 75 + t] = keep_s[rank_s[t]] ? 1.f : 0.f;
}

// ------------------------------- launch --------------------------------------
extern "C" void kernel_launch(void* const* d_in, const int* in_sizes, int n_in,
                              void* d_out, int out_size, void* d_ws, size_t ws_size,
                              hipStream_t stream) {
  (void)in_sizes; (void)n_in; (void)out_size; (void)ws_size;
  const float* x     = (const float*)d_in[0];
  const float* fw0   = (const float*)d_in[1];
  const float* fb0   = (const float*)d_in[2];
  const float* fw1   = (const float*)d_in[3];
  const float* fb1   = (const float*)d_in[4];
  const float* fw2   = (const float*)d_in[5];
  const float* fb2   = (const float*)d_in[6];
  const float* fw3   = (const float*)d_in[7];
  const float* fb3   = (const float*)d_in[8];
  const float* fw4   = (const float*)d_in[9];
  const float* fb4   = (const float*)d_in[10];
  const float* rpw_w = (const float*)d_in[11];
  const float* rpw_b = (const float*)d_in[12];
  const float* cls_w = (const float*)d_in[13];
  const float* cls_b = (const float*)d_in[14];
  const float* reg_w = (const float*)d_in[15];
  const float* reg_b = (const float*)d_in[16];
  const float* fc_w  = (const float*)d_in[17];
  const float* fc_b  = (const float*)d_in[18];
  float* out = (float*)d_out;
  char* ws = (char*)d_ws;

  // activation buffers (fp16 hi/lo planes)
  _Float16* I0h = (_Float16*)(ws + A_OFF);
  _Float16* I0l = I0h + I0_E;
  _Float16* I1h = (_Float16*)(ws + B_OFF);
  _Float16* I1l = I1h + I1_E;
  _Float16* I2h = (_Float16*)(ws + A_OFF);
  _Float16* I2l = I2h + I2_E;
  _Float16* I3h = (_Float16*)(ws + B_OFF);
  _Float16* I3l = I3h + I3_E;
  _Float16* I4h = (_Float16*)(ws + A_OFF);
  _Float16* I4l = I4h + I4_E;
  float* feat  = (float*)(ws + A_OFF + (size_t)I4_E * 4);            // 3.2MB
  float* rp512 = (float*)(ws + A_OFF + (size_t)I4_E * 4 + 3211264);  // 1.6MB
  float* part  = (float*)(ws + P_OFF);                               // partials

  // converted weights [tap*kch][co][32] hi/lo
  _Float16* w1h = (_Float16*)(ws + W_OFF);                _Float16* w1l = w1h + 73728;
  _Float16* w2h = (_Float16*)(ws + W_OFF + 294912);       _Float16* w2l = w2h + 294912;
  _Float16* w3h = (_Float16*)(ws + W_OFF + 1474560);      _Float16* w3l = w3h + 1179648;
  _Float16* w4h = (_Float16*)(ws + W_OFF + 6193152);      _Float16* w4l = w4h + 2359296;
  _Float16* wrh = (_Float16*)(ws + W_OFF + 15630336);     _Float16* wrl = wrh + 2359296;

  // weight conversion
  wcvt<<<(73728 + 255) / 256, 256, 0, stream>>>(fw1, w1h, w1l, 128, 64);
  wcvt<<<(294912 + 255) / 256, 256, 0, stream>>>(fw2, w2h, w2l, 256, 128);
  wcvt<<<(1179648 + 255) / 256, 256, 0, stream>>>(fw3, w3h, w3l, 512, 256);
  wcvt<<<(2359296 + 255) / 256, 256, 0, stream>>>(fw4, w4h, w4l, 512, 512);
  wcvt<<<(2359296 + 255) / 256, 256, 0, stream>>>(rpw_w, wrh, wrl, 512, 512);

  // pad rings for I0, I1
  zero_ring<<<512, 256, 0, stream>>>(I0h, I0l, 114, 64);
  zero_ring<<<512, 256, 0, stream>>>(I1h, I1l, 58, 128);

  // L0 direct conv
  conv_l0<<<32 * 49, 256, 0, stream>>>(x, fw0, fb0, I0h, I0l);

  // L1: 64->128 @112, block co128 x sp128, KPH=1
  convpool<64, 128, 112, 128, 128, 9, 1, 0><<<dim3(3136, 1, 1), 256, 0, stream>>>(
      I0h, I0l, w1h, w1l, fb1, I1h, I1l, nullptr);
  zero_ring<<<512, 256, 0, stream>>>(I2h, I2l, 30, 256);   // I0 region now free
  // L2: 128->256 @56, block co256 x sp64, KPH=2
  convpool<128, 256, 56, 256, 64, 9, 2, 0><<<dim3(1568, 1, 1), 256, 0, stream>>>(
      I1h, I1l, w2h, w2l, fb2, I2h, I2l, nullptr);
  zero_ring<<<512, 256, 0, stream>>>(I3h, I3l, 16, 512);   // I1 region now free
  // L3: 256->512 @28, KPH=2
  convpool<256, 512, 28, 256, 64, 9, 2, 0><<<dim3(392, 2, 1), 256, 0, stream>>>(
      I2h, I2l, w3h, w3l, fb3, I3h, I3l, nullptr);
  // L4: 512->512 @14, split-tap x3 -> partials, KPH=2, then finish
  convpool<512, 512, 14, 256, 64, 3, 2, 1><<<dim3(98, 2, 3), 256, 0, stream>>>(
      I3h, I3l, w4h, w4l, nullptr, nullptr, nullptr, part);
  l4_finish<<<(1568 * 128 + 255) / 256, 256, 0, stream>>>(part, fb4, I4h, I4l, feat);

  // RPN: split-tap x9 -> partials, then finish
  rpn_partial<<<dim3(13, 4, 9), 256, 0, stream>>>(I4h, I4l, wrh, wrl, part);
  rpn_finish<<<(800 * 128 + 255) / 256, 256, 0, stream>>>(part, rpw_b, rp512);

  heads_kernel<<<(12000 + 255) / 256, 256, 0, stream>>>(rp512, cls_w, cls_b, reg_w, reg_b, out);
  fc_kernel<<<dim3(32, 20), 256, 0, stream>>>(feat, fc_w, fc_b, out);
  bbox_nms_kernel<<<BATCH, 128, 0, stream>>>(out);
}

// Round 6
// 1001.766 us; speedup vs baseline: 23.8170x; 1.0153x over previous
//
#include <hip/hip_runtime.h>
#include <math.h>

// VGG_RP round 6: phase-wide A-register preload (one L2-latency wait per
// phase instead of per K32 sub-chunk), __launch_bounds__(256,2) to allow the
// ~130-VGPR live set, s_setprio(1) around MFMA clusters. Swizzled LDS B
// staging (0 bank conflicts, verified r5) unchanged; math bit-identical.
//
// d_out (float32), out_size = 24640:
//   [0,640) logits | [640,3040) rp_cls | [3040,12640) rp_reg
//   [12640,22240) bboxes | [22240,24640) keep

#define OFF_LOGITS 0
#define OFF_CLS    640
#define OFF_REG    3040
#define OFF_BOXES  12640
#define OFF_KEEP   22240

constexpr int BATCH = 32;

typedef _Float16 h8 __attribute__((ext_vector_type(8)));
typedef _Float16 h4 __attribute__((ext_vector_type(4)));
typedef float    f4 __attribute__((ext_vector_type(4)));

#define MFMA16(a, b, c) __builtin_amdgcn_mfma_f32_16x16x32_f16(a, b, c, 0, 0, 0)

#if defined(__has_builtin)
#  if __has_builtin(__builtin_amdgcn_global_load_lds)
#    define HAS_GLL 1
#  endif
#endif

// async global->LDS, 16B per lane. lbase must be wave-uniform (HW adds lane*16).
__device__ __forceinline__ void stage16(const _Float16* g, _Float16* lbase, int lane) {
#ifdef HAS_GLL
  __builtin_amdgcn_global_load_lds((const __attribute__((address_space(1))) void*)g,
                                   (__attribute__((address_space(3))) void*)lbase,
                                   16, 0, 0);
#else
  *reinterpret_cast<h8*>(lbase + lane * 8) = *reinterpret_cast<const h8*>(g);
#endif
}

// ---------------- workspace layout (bytes) ----------------
constexpr size_t A_OFF = 0;              // I0 -> I2 -> {I4, feat, rp512, partials}
constexpr size_t B_OFF = 106463232;      // I1 -> I3
constexpr size_t W_OFF = 161579008;      // converted weights
constexpr size_t P_OFF = A_OFF + 8388608;  // partials (overlay dead I2 region)

constexpr int I0_E = 26615808;   // 32*114*114*64
constexpr int I1_E = 13778944;   // 32*58*58*128
constexpr int I2_E = 7372800;    // 32*30*30*256
constexpr int I3_E = 4194304;    // 32*16*16*512
constexpr int I4_E = 802816;     // 32*7*7*512

// ---------------- weight convert: OIHW fp32 -> [tap*kch][co][32] hi/lo ------
__global__ __launch_bounds__(256)
void wcvt(const float* __restrict__ src, _Float16* __restrict__ dHi,
          _Float16* __restrict__ dLo, int COUT, int CIN) {
  const int total = COUT * CIN * 9;
  for (int idx = blockIdx.x * 256 + threadIdx.x; idx < total; idx += gridDim.x * 256) {
    const int co = idx / (CIN * 9);
    const int r = idx % (CIN * 9);
    const int ci = r / 9, tap = r % 9;
    const float v = src[idx];
    const _Float16 h = (_Float16)v;
    const int o = ((tap * (CIN >> 5) + (ci >> 5)) * COUT + co) * 32 + (ci & 31);
    dHi[o] = h;
    dLo[o] = (_Float16)(v - (float)h);
  }
}

// ---------------- zero the 1-px pad ring of a CL fp16 buffer ----------------
__global__ __launch_bounds__(256)
void zero_ring(_Float16* __restrict__ hi, _Float16* __restrict__ lo, int P, int C) {
  const int c8n = C / 8, cells = 4 * P - 4;
  const int tot = 32 * cells * c8n;
  for (int idx = blockIdx.x * 256 + threadIdx.x; idx < tot; idx += gridDim.x * 256) {
    const int c8 = idx % c8n;
    const int cell = (idx / c8n) % cells;
    const int n = idx / (c8n * cells);
    int y, xx;
    if (cell < 2 * P) { y = (cell < P) ? 0 : (P - 1); xx = cell % P; }
    else { const int q = cell - 2 * P; y = 1 + (q >> 1); xx = (q & 1) ? (P - 1) : 0; }
    const long o = ((long)(n * P + y) * P + xx) * C + c8 * 8;
    h8 z = {};
    *reinterpret_cast<h8*>(hi + o) = z;
    *reinterpret_cast<h8*>(lo + o) = z;
  }
}

// ---------------- L0: 3->64 direct fp32 conv+pool, emit fp16 CL padded ------
__global__ __launch_bounds__(256)
void conv_l0(const float* __restrict__ x, const float* __restrict__ w0,
             const float* __restrict__ b0, _Float16* __restrict__ outHi,
             _Float16* __restrict__ outLo) {
  const int bid = blockIdx.x;
  const int tx0 = (bid % 7) * 16, ty0 = ((bid / 7) % 7) * 16, n = bid / 49;
  __shared__ float sIn[3 * 34 * 34];
  __shared__ float sW[1728];
  __shared__ float sB[64];
  const int tid = threadIdx.x;
  for (int idx = tid; idx < 3 * 34 * 34; idx += 256) {
    const int ci = idx / 1156, rem = idx % 1156, r = rem / 34, cc = rem % 34;
    const int y = 2 * ty0 - 1 + r, xx = 2 * tx0 - 1 + cc;
    float v = 0.f;
    if ((unsigned)y < 224u && (unsigned)xx < 224u)
      v = x[((n * 3 + ci) * 224 + y) * 224 + xx];
    sIn[idx] = v;
  }
  for (int idx = tid; idx < 1728; idx += 256) sW[idx] = w0[idx];
  if (tid < 64) sB[tid] = b0[tid];
  __syncthreads();

  const int tpy = tid / 16, tpx = tid % 16;
  float win[3][4][4];
  #pragma unroll
  for (int ci = 0; ci < 3; ++ci)
    #pragma unroll
    for (int dr = 0; dr < 4; ++dr)
      #pragma unroll
      for (int dc = 0; dc < 4; ++dc)
        win[ci][dr][dc] = sIn[ci * 1156 + (2 * tpy + dr) * 34 + (2 * tpx + dc)];

  const long ob = ((long)(n * 114 + ty0 + tpy + 1) * 114 + tx0 + tpx + 1) * 64;
  for (int co4 = 0; co4 < 16; ++co4) {
    h4 hh, ll;
    #pragma unroll
    for (int j = 0; j < 4; ++j) {
      const int co = co4 * 4 + j;
      float a00 = 0.f, a01 = 0.f, a10 = 0.f, a11 = 0.f;
      #pragma unroll
      for (int ci = 0; ci < 3; ++ci)
        #pragma unroll
        for (int ky = 0; ky < 3; ++ky)
          #pragma unroll
          for (int kx = 0; kx < 3; ++kx) {
            const float wv = sW[co * 27 + ci * 9 + ky * 3 + kx];
            a00 = fmaf(win[ci][ky][kx], wv, a00);
            a01 = fmaf(win[ci][ky][kx + 1], wv, a01);
            a10 = fmaf(win[ci][ky + 1][kx], wv, a10);
            a11 = fmaf(win[ci][ky + 1][kx + 1], wv, a11);
          }
      const float p = fmaxf(fmaxf(fmaxf(a00, a01), fmaxf(a10, a11)) + sB[co], 0.f);
      const _Float16 h = (_Float16)p;
      hh[j] = h;
      ll[j] = (_Float16)(p - (float)h);
    }
    *reinterpret_cast<h4*>(outHi + ob + co4 * 4) = hh;
    *reinterpret_cast<h4*>(outLo + ob + co4 * 4) = ll;
  }
}

// ---------------- main conv(+pool) implicit GEMM, LDS-pipelined -------------
// Block: 4 waves (NCOW x NSPW). B tile [BSP][32] per k-chunk, KPH chunks per
// phase, double-buffered in LDS via global_load_lds (swizzled, conflict-free).
// A-fragments for the WHOLE phase preloaded into registers before staging so
// the L2 latency is paid once per phase and hides under the prior MFMAs.
// MODE 0: fused pool/bias/relu epilogue. MODE 1: fp32 partials (split-tap).
template<int CIN, int COUT, int H, int BCO, int BSP, int TG, int KPH, int MODE>
__global__ __launch_bounds__(256, 2)
void convpool(const _Float16* __restrict__ inHi, const _Float16* __restrict__ inLo,
              const _Float16* __restrict__ wHi, const _Float16* __restrict__ wLo,
              const float* __restrict__ bias, _Float16* __restrict__ outHi,
              _Float16* __restrict__ outLo, float* __restrict__ outF) {
  constexpr int W = H, Hp = H / 2, Wp = W / 2, PW = W + 2, POW = Wp + 2;
  constexpr int NCOW = BCO / 64, NSPW = BSP / 64;
  static_assert(NCOW * NSPW == 4, "4 waves");
  constexpr int KCH = CIN / 32;
  constexpr int NCH = TG * KCH;
  constexpr int NPH = NCH / KPH;
  static_assert(NCH % KPH == 0, "even phases");
  constexpr int NISS = BSP / 64;
  constexpr int SPTOT = 32 * H * W;
  constexpr int TSZ = BSP * 32;  // elements per (hl, j) tile
  __align__(16) __shared__ _Float16 sB[2 * 2 * KPH * TSZ];
  // tile base: ((buf*2 + hl)*KPH + j) * TSZ
  #define TIDX(buf, hl, j) ((((buf) * 2 + (hl)) * KPH + (j)) * TSZ)

  const int tid = threadIdx.x;
  const int lane = tid & 63, wv = tid >> 6;
  const int c = lane & 15, kq = lane >> 4;
  const int cow = blockIdx.y * BCO + (wv % NCOW) * 64;
  const int spl = (wv / NCOW) * 64;
  const int sblk = blockIdx.x * BSP;
  const int tap0 = (TG == 9) ? 0 : blockIdx.z * TG;

  // staging source base incl. inverse-swizzled 16B slot (thread stages row
  // sl = i*64 + tid/4, local slot tid&3 -> global slot (tid&3)^((sl>>1)&3))
  int gstage[NISS];
  #pragma unroll
  for (int i = 0; i < NISS; ++i) {
    const int sl = i * 64 + tid / 4;
    const int sg = sblk + sl;
    const int ry = sg & 1, tt = sg >> 1;
    const int x = tt % W, u = tt / W;
    const int py = u % Hp, n = u / Hp;
    gstage[i] = ((n * (H + 2) + 2 * py + ry) * PW + x) * CIN +
                (((tid & 3) ^ ((sl >> 1) & 3)) * 8);
  }
  // ds_read offsets (swizzled) per nt
  int dsoff[4];
  #pragma unroll
  for (int nt = 0; nt < 4; ++nt) {
    const int row = spl + nt * 16 + c;
    dsoff[nt] = row * 32 + ((kq ^ ((row >> 1) & 3)) * 8);
  }

  // prologue: stage phase 0 (KPH chunks) into buf 0
  #pragma unroll
  for (int j = 0; j < KPH; ++j) {
    const int tap = tap0 + j / KCH, kc = j % KCH;
    const int tb = ((tap / 3) * PW + (tap % 3)) * CIN + kc * 32;
    #pragma unroll
    for (int i = 0; i < NISS; ++i) {
      stage16(inHi + gstage[i] + tb, &sB[TIDX(0, 0, j) + i * 2048 + wv * 512], lane);
      stage16(inLo + gstage[i] + tb, &sB[TIDX(0, 1, j) + i * 2048 + wv * 512], lane);
    }
  }
  __syncthreads();

  f4 acc[4][4] = {};
  int cur = 0;
  for (int ph = 0; ph < NPH; ++ph) {
    // A preload for ALL sub-chunks of this phase (dense 1KB per instruction),
    // issued before staging so the A vmcnt-wait doesn't drain the stage queue
    // and j1's latency hides under j0's MFMAs.
    h8 aH[KPH][4], aL[KPH][4];
    #pragma unroll
    for (int j = 0; j < KPH; ++j) {
      const int ch = ph * KPH + j;
      const int tap = tap0 + ch / KCH;
      const int kc = ch % KCH;
      const long abase = ((long)(tap * KCH + kc) * COUT + cow) * 32;
      #pragma unroll
      for (int mt = 0; mt < 4; ++mt) {
        const long ao = abase + (mt * 16 + c) * 32 + kq * 8;
        aH[j][mt] = *reinterpret_cast<const h8*>(wHi + ao);
        aL[j][mt] = *reinterpret_cast<const h8*>(wLo + ao);
      }
    }
    // stage next phase (async, drains at the barrier)
    if (ph + 1 < NPH) {
      #pragma unroll
      for (int j2 = 0; j2 < KPH; ++j2) {
        const int ch2 = (ph + 1) * KPH + j2;
        const int tap2 = tap0 + ch2 / KCH;
        const int tb2 = ((tap2 / 3) * PW + (tap2 % 3)) * CIN + (ch2 % KCH) * 32;
        #pragma unroll
        for (int i = 0; i < NISS; ++i) {
          stage16(inHi + gstage[i] + tb2,
                  &sB[TIDX(cur ^ 1, 0, j2) + i * 2048 + wv * 512], lane);
          stage16(inLo + gstage[i] + tb2,
                  &sB[TIDX(cur ^ 1, 1, j2) + i * 2048 + wv * 512], lane);
        }
      }
    }
    // compute sub-chunks
    #pragma unroll
    for (int j = 0; j < KPH; ++j) {
      h8 bH[4], bL[4];
      #pragma unroll
      for (int nt = 0; nt < 4; ++nt) {
        bH[nt] = *reinterpret_cast<const h8*>(&sB[TIDX(cur, 0, j) + dsoff[nt]]);
        bL[nt] = *reinterpret_cast<const h8*>(&sB[TIDX(cur, 1, j) + dsoff[nt]]);
      }
      __builtin_amdgcn_s_setprio(1);
      #pragma unroll
      for (int mt = 0; mt < 4; ++mt)
        #pragma unroll
        for (int nt = 0; nt < 4; ++nt)
          acc[mt][nt] = MFMA16(aH[j][mt], bH[nt], acc[mt][nt]);
      #pragma unroll
      for (int mt = 0; mt < 4; ++mt)
        #pragma unroll
        for (int nt = 0; nt < 4; ++nt)
          acc[mt][nt] = MFMA16(aH[j][mt], bL[nt], acc[mt][nt]);
      #pragma unroll
      for (int mt = 0; mt < 4; ++mt)
        #pragma unroll
        for (int nt = 0; nt < 4; ++nt)
          acc[mt][nt] = MFMA16(aL[j][mt], bH[nt], acc[mt][nt]);
      __builtin_amdgcn_s_setprio(0);
    }
    __syncthreads();
    cur ^= 1;
  }
  #undef TIDX

  const int r4 = lane >> 4;
  if (MODE == 1) {
    // fp32 partials, no bias/pool
    #pragma unroll
    for (int mt = 0; mt < 4; ++mt) {
      const int co0 = cow + mt * 16 + r4 * 4;
      #pragma unroll
      for (int nt = 0; nt < 4; ++nt) {
        const int s = sblk + spl + nt * 16 + c;
        *reinterpret_cast<f4*>(outF + ((long)blockIdx.z * SPTOT + s) * COUT + co0) =
            acc[mt][nt];
      }
    }
  } else {
    // fused 2x2 pool + bias + relu + hi/lo CL write
    #pragma unroll
    for (int mt = 0; mt < 4; ++mt) {
      const int co0 = cow + mt * 16 + r4 * 4;
      const f4 bi = *reinterpret_cast<const f4*>(bias + co0);
      #pragma unroll
      for (int nt = 0; nt < 4; ++nt) {
        f4 v = acc[mt][nt];
        #pragma unroll
        for (int r = 0; r < 4; ++r) {
          const float m1 = fmaxf(v[r], __shfl_xor(v[r], 1, 64));
          v[r] = fmaxf(m1, __shfl_xor(m1, 2, 64));
        }
        if ((lane & 3) == 0) {
          const int s = sblk + spl + nt * 16 + c;
          const int ps = s >> 2;
          const int n = ps / (Hp * Wp), rem = ps % (Hp * Wp);
          const int py = rem / Wp, px = rem % Wp;
          h4 hh, ll;
          #pragma unroll
          for (int r = 0; r < 4; ++r) {
            const float p = fmaxf(v[r] + bi[r], 0.f);
            const _Float16 h = (_Float16)p;
            hh[r] = h;
            ll[r] = (_Float16)(p - (float)h);
          }
          const long oa = ((long)((n * (Hp + 2) + py + 1) * POW + px + 1)) * COUT + co0;
          *reinterpret_cast<h4*>(outHi + oa) = hh;
          *reinterpret_cast<h4*>(outLo + oa) = ll;
        }
      }
    }
  }
}

// ---------------- l4_finish: sum 3 partials, pool, bias, relu ---------------
__global__ __launch_bounds__(256)
void l4_finish(const float* __restrict__ part, const float* __restrict__ bias,
               _Float16* __restrict__ I4h, _Float16* __restrict__ I4l,
               float* __restrict__ feat) {
  const int t = blockIdx.x * 256 + threadIdx.x;
  if (t >= 1568 * 128) return;
  const int co0 = (t % 128) * 4, p = t / 128;
  f4 m;
  #pragma unroll
  for (int q = 0; q < 4; ++q) {
    const long s = 4L * p + q;
    f4 v = *reinterpret_cast<const f4*>(part + s * 512 + co0);
    v += *reinterpret_cast<const f4*>(part + (6272 + s) * 512 + co0);
    v += *reinterpret_cast<const f4*>(part + (12544 + s) * 512 + co0);
    if (q == 0) m = v;
    else {
      #pragma unroll
      for (int r = 0; r < 4; ++r) m[r] = fmaxf(m[r], v[r]);
    }
  }
  const f4 bi = *reinterpret_cast<const f4*>(bias + co0);
  h4 hh, ll;
  const int n = p / 49, pix = p % 49;
  #pragma unroll
  for (int r = 0; r < 4; ++r) {
    const float pv = fmaxf(m[r] + bi[r], 0.f);
    const _Float16 h = (_Float16)pv;
    hh[r] = h;
    ll[r] = (_Float16)(pv - (float)h);
    feat[((long)(n * 512 + co0 + r)) * 49 + pix] = pv;
  }
  *reinterpret_cast<h4*>(I4h + (long)p * 512 + co0) = hh;
  *reinterpret_cast<h4*>(I4l + (long)p * 512 + co0) = ll;
}

// ---------------- RPN partial: one tap per blockIdx.z, K=512 GEMM -----------
__global__ __launch_bounds__(256)
void rpn_partial(const _Float16* __restrict__ inHi, const _Float16* __restrict__ inLo,
                 const _Float16* __restrict__ wHi, const _Float16* __restrict__ wLo,
                 float* __restrict__ part) {
  const int lane = threadIdx.x & 63, wv = threadIdx.x >> 6;
  const int cow = blockIdx.y * 128 + wv * 32;
  const int sblk = blockIdx.x * 64;
  const int tap = blockIdx.z, ky = tap / 3, kx = tap % 3;
  const int c = lane & 15, kq = lane >> 4;

  int baseB[4];
  #pragma unroll
  for (int nt = 0; nt < 4; ++nt) {
    int s = sblk + nt * 16 + c;
    if (s > 799) s = 799;
    const int n = s / 25, pix = s % 25, py = pix / 5, px = pix % 5;
    baseB[nt] = ((n * 7 + py + ky) * 7 + px + kx) * 512;
  }

  f4 acc[2][4] = {};
  for (int kch = 0; kch < 16; ++kch) {
    h8 aH[2], aL[2], bH[4], bL[4];
    const long abase = ((long)(tap * 16 + kch) * 512 + cow) * 32;
    #pragma unroll
    for (int mt = 0; mt < 2; ++mt) {
      const long ao = abase + (mt * 16 + c) * 32 + kq * 8;
      aH[mt] = *reinterpret_cast<const h8*>(wHi + ao);
      aL[mt] = *reinterpret_cast<const h8*>(wLo + ao);
    }
    #pragma unroll
    for (int nt = 0; nt < 4; ++nt) {
      const int bo = baseB[nt] + kch * 32 + kq * 8;
      bH[nt] = *reinterpret_cast<const h8*>(inHi + bo);
      bL[nt] = *reinterpret_cast<const h8*>(inLo + bo);
    }
    #pragma unroll
    for (int mt = 0; mt < 2; ++mt)
      #pragma unroll
      for (int nt = 0; nt < 4; ++nt)
        acc[mt][nt] = MFMA16(aH[mt], bH[nt], acc[mt][nt]);
    #pragma unroll
    for (int mt = 0; mt < 2; ++mt)
      #pragma unroll
      for (int nt = 0; nt < 4; ++nt)
        acc[mt][nt] = MFMA16(aH[mt], bL[nt], acc[mt][nt]);
    #pragma unroll
    for (int mt = 0; mt < 2; ++mt)
      #pragma unroll
      for (int nt = 0; nt < 4; ++nt)
        acc[mt][nt] = MFMA16(aL[mt], bH[nt], acc[mt][nt]);
  }

  const int r4 = lane >> 4;
  #pragma unroll
  for (int mt = 0; mt < 2; ++mt) {
    const int co0 = cow + mt * 16 + r4 * 4;
    #pragma unroll
    for (int nt = 0; nt < 4; ++nt) {
      const int s = sblk + nt * 16 + c;
      if (s < 800)
        *reinterpret_cast<f4*>(part + ((long)tap * 800 + s) * 512 + co0) = acc[mt][nt];
    }
  }
}

// ---------------- rpn_finish: sum 9 taps + bias + relu -> rp512 CL ----------
__global__ __launch_bounds__(256)
void rpn_finish(const float* __restrict__ part, const float* __restrict__ bias,
                float* __restrict__ rp512) {
  const int t = blockIdx.x * 256 + threadIdx.x;
  if (t >= 800 * 128) return;
  const int co0 = (t % 128) * 4, s = t / 128;
  f4 acc = *reinterpret_cast<const f4*>(bias + co0);
  #pragma unroll
  for (int g = 0; g < 9; ++g)
    acc += *reinterpret_cast<const f4*>(part + ((long)g * 800 + s) * 512 + co0);
  f4 o;
  #pragma unroll
  for (int r = 0; r < 4; ++r) o[r] = fmaxf(acc[r], 0.f);
  *reinterpret_cast<f4*>(rp512 + (long)s * 512 + co0) = o;
}

// ---------------- 1x1 heads (fp32, CL input), straight to d_out --------------
__global__ __launch_bounds__(256)
void heads_kernel(const float* __restrict__ rp512,
                  const float* __restrict__ cls_w, const float* __restrict__ cls_b,
                  const float* __restrict__ reg_w, const float* __restrict__ reg_b,
                  float* __restrict__ out) {
  const int idx = blockIdx.x * 256 + threadIdx.x;
  if (idx >= 32 * 25 * 15) return;
  const int o = idx % 15, pix = (idx / 15) % 25, n = idx / 375;
  const float* __restrict__ ip = rp512 + ((long)(n * 25 + pix)) * 512;
  const float* __restrict__ wvp = (o < 3) ? (cls_w + o * 512) : (reg_w + (o - 3) * 512);
  float acc = 0.f;
  for (int k = 0; k < 512; k += 4) {
    const f4 a = *reinterpret_cast<const f4*>(ip + k);
    const f4 b = *reinterpret_cast<const f4*>(wvp + k);
    acc = fmaf(a[0], b[0], acc); acc = fmaf(a[1], b[1], acc);
    acc = fmaf(a[2], b[2], acc); acc = fmaf(a[3], b[3], acc);
  }
  if (o < 3) {
    acc += cls_b[o];
    out[OFF_CLS + n * 75 + o * 25 + pix] = 1.f / (1.f + expf(-acc));
  } else {
    acc += reg_b[o - 3];
    out[OFF_REG + n * 300 + (o - 3) * 25 + pix] = acc;
  }
}

// ---------------- FC: grid (32,20), float4 + wave reduce ---------------------
__global__ __launch_bounds__(256)
void fc_kernel(const float* __restrict__ feat, const float* __restrict__ fw,
               const float* __restrict__ fb, float* __restrict__ out) {
  const int n = blockIdx.x, j = blockIdx.y;
  const float* __restrict__ ip = feat + (long)n * 25088;
  const float* __restrict__ wj = fw + (long)j * 25088;
  float acc = 0.f;
  for (int k = threadIdx.x * 4; k < 25088; k += 1024) {
    const f4 a = *reinterpret_cast<const f4*>(ip + k);
    const f4 b = *reinterpret_cast<const f4*>(wj + k);
    acc = fmaf(a[0], b[0], acc); acc = fmaf(a[1], b[1], acc);
    acc = fmaf(a[2], b[2], acc); acc = fmaf(a[3], b[3], acc);
  }
  #pragma unroll
  for (int m = 32; m >= 1; m >>= 1) acc += __shfl_xor(acc, m, 64);
  __shared__ float red[4];
  const int wv = threadIdx.x >> 6;
  if ((threadIdx.x & 63) == 0) red[wv] = acc;
  __syncthreads();
  if (threadIdx.x == 0)
    out[OFF_LOGITS + n * 20 + j] = red[0] + red[1] + red[2] + red[3] + fb[j];
}

// ---------------- deparam bboxes + faithful buggy-IoU greedy NMS -------------
__global__ __launch_bounds__(128)
void bbox_nms_kernel(float* __restrict__ out) {
  const int n = blockIdx.x;
  const int t = threadIdx.x;
  __shared__ float bx0[75], by0[75], bx1[75], by1[75], area[75], sc[75];
  __shared__ int rank_s[75], order_s[75], keep_s[75];

  if (t < 75) {
    const int g1 = t / 15, g2 = (t / 3) % 5, a = t % 3;
    const float aw = (a == 0) ? 56.f : (a == 1 ? 112.f : 224.f);
    const float r0 = out[OFF_REG + n * 300 + 4 * t + 0];
    const float r1 = out[OFF_REG + n * 300 + 4 * t + 1];
    const float r2 = out[OFF_REG + n * 300 + 4 * t + 2];
    const float r3 = out[OFF_REG + n * 300 + 4 * t + 3];
    const float cx = r0 * aw + (float)g1;
    const float cy = r1 * aw + (float)g2;
    const float w_ = expf(r2) * aw;
    const float h_ = expf(r3) * aw;
    const float x0 = cx - 0.5f * w_, y0 = cy - 0.5f * h_;
    const float x1 = cx + 0.5f * w_, y1 = cy + 0.5f * h_;
    bx0[t] = x0; by0[t] = y0; bx1[t] = x1; by1[t] = y1;
    area[t] = (x1 - x0 + 1.f) * (y1 - y0 + 1.f);
    out[OFF_BOXES + n * 300 + 4 * t + 0] = x0;
    out[OFF_BOXES + n * 300 + 4 * t + 1] = y0;
    out[OFF_BOXES + n * 300 + 4 * t + 2] = x1;
    out[OFF_BOXES + n * 300 + 4 * t + 3] = y1;
    sc[t] = out[OFF_CLS + n * 75 + t];
    keep_s[t] = 1;
  }
  __syncthreads();
  if (t < 75) {
    const float si = sc[t];
    int rk = 0;
    for (int j = 0; j < 75; ++j) {
      const float sj = sc[j];
      rk += (sj > si) || (sj == si && j < t);
    }
    rank_s[t] = rk;
    order_s[rk] = t;
  }
  __syncthreads();
  for (int i = 0; i < 74; ++i) {
    if (keep_s[i]) {
      const int bi = order_s[i];
      if (t > i && t < 75) {
        const int bj = order_s[t];
        const float xA = fmaxf(bx0[bi], bx0[bj]);
        const float yA = fmaxf(by0[bi], by0[bj]);
        const float xB = fminf(bx1[bi], bx1[bj]);
        const float yB = fminf(by1[bi], by1[bj]);
        const float inter = fmaxf(0.f, xB - xA + 1.f) * fmaxf(0.f, yB - yA + 1.f);
        const float iou = inter / area[bi] + area[bj] - inter;  // faithful bug
        if (iou > 0.7f) keep_s[t] = 0;
      }
    }
    __syncthreads();
  }
  if (t < 75) out[OFF_KEEP + n * 75 + t] = keep_s[rank_s[t]] ? 1.f : 0.f;
}

// ------------------------------- launch --------------------------------------
extern "C" void kernel_launch(void* const* d_in, const int* in_sizes, int n_in,
                              void* d_out, int out_size, void* d_ws, size_t ws_size,
                              hipStream_t stream) {
  (void)in_sizes; (void)n_in; (void)out_size; (void)ws_size;
  const float* x     = (const float*)d_in[0];
  const float* fw0   = (const float*)d_in[1];
  const float* fb0   = (const float*)d_in[2];
  const float* fw1   = (const float*)d_in[3];
  const float* fb1   = (const float*)d_in[4];
  const float* fw2   = (const float*)d_in[5];
  const float* fb2   = (const float*)d_in[6];
  const float* fw3   = (const float*)d_in[7];
  const float* fb3   = (const float*)d_in[8];
  const float* fw4   = (const float*)d_in[9];
  const float* fb4   = (const float*)d_in[10];
  const float* rpw_w = (const float*)d_in[11];
  const float* rpw_b = (const float*)d_in[12];
  const float* cls_w = (const float*)d_in[13];
  const float* cls_b = (const float*)d_in[14];
  const float* reg_w = (const float*)d_in[15];
  const float* reg_b = (const float*)d_in[16];
  const float* fc_w  = (const float*)d_in[17];
  const float* fc_b  = (const float*)d_in[18];
  float* out = (float*)d_out;
  char* ws = (char*)d_ws;

  // activation buffers (fp16 hi/lo planes)
  _Float16* I0h = (_Float16*)(ws + A_OFF);
  _Float16* I0l = I0h + I0_E;
  _Float16* I1h = (_Float16*)(ws + B_OFF);
  _Float16* I1l = I1h + I1_E;
  _Float16* I2h = (_Float16*)(ws + A_OFF);
  _Float16* I2l = I2h + I2_E;
  _Float16* I3h = (_Float16*)(ws + B_OFF);
  _Float16* I3l = I3h + I3_E;
  _Float16* I4h = (_Float16*)(ws + A_OFF);
  _Float16* I4l = I4h + I4_E;
  float* feat  = (float*)(ws + A_OFF + (size_t)I4_E * 4);            // 3.2MB
  float* rp512 = (float*)(ws + A_OFF + (size_t)I4_E * 4 + 3211264);  // 1.6MB
  float* part  = (float*)(ws + P_OFF);                               // partials

  // converted weights [tap*kch][co][32] hi/lo
  _Float16* w1h = (_Float16*)(ws + W_OFF);                _Float16* w1l = w1h + 73728;
  _Float16* w2h = (_Float16*)(ws + W_OFF + 294912);       _Float16* w2l = w2h + 294912;
  _Float16* w3h = (_Float16*)(ws + W_OFF + 1474560);      _Float16* w3l = w3h + 1179648;
  _Float16* w4h = (_Float16*)(ws + W_OFF + 6193152);      _Float16* w4l = w4h + 2359296;
  _Float16* wrh = (_Float16*)(ws + W_OFF + 15630336);     _Float16* wrl = wrh + 2359296;

  // weight conversion
  wcvt<<<(73728 + 255) / 256, 256, 0, stream>>>(fw1, w1h, w1l, 128, 64);
  wcvt<<<(294912 + 255) / 256, 256, 0, stream>>>(fw2, w2h, w2l, 256, 128);
  wcvt<<<(1179648 + 255) / 256, 256, 0, stream>>>(fw3, w3h, w3l, 512, 256);
  wcvt<<<(2359296 + 255) / 256, 256, 0, stream>>>(fw4, w4h, w4l, 512, 512);
  wcvt<<<(2359296 + 255) / 256, 256, 0, stream>>>(rpw_w, wrh, wrl, 512, 512);

  // pad rings for I0, I1
  zero_ring<<<512, 256, 0, stream>>>(I0h, I0l, 114, 64);
  zero_ring<<<512, 256, 0, stream>>>(I1h, I1l, 58, 128);

  // L0 direct conv
  conv_l0<<<32 * 49, 256, 0, stream>>>(x, fw0, fb0, I0h, I0l);

  // L1: 64->128 @112, block co128 x sp128, KPH=1
  convpool<64, 128, 112, 128, 128, 9, 1, 0><<<dim3(3136, 1, 1), 256, 0, stream>>>(
      I0h, I0l, w1h, w1l, fb1, I1h, I1l, nullptr);
  zero_ring<<<512, 256, 0, stream>>>(I2h, I2l, 30, 256);   // I0 region now free
  // L2: 128->256 @56, block co256 x sp64, KPH=2
  convpool<128, 256, 56, 256, 64, 9, 2, 0><<<dim3(1568, 1, 1), 256, 0, stream>>>(
      I1h, I1l, w2h, w2l, fb2, I2h, I2l, nullptr);
  zero_ring<<<512, 256, 0, stream>>>(I3h, I3l, 16, 512);   // I1 region now free
  // L3: 256->512 @28, KPH=2
  convpool<256, 512, 28, 256, 64, 9, 2, 0><<<dim3(392, 2, 1), 256, 0, stream>>>(
      I2h, I2l, w3h, w3l, fb3, I3h, I3l, nullptr);
  // L4: 512->512 @14, split-tap x3 -> partials, KPH=2, then finish
  convpool<512, 512, 14, 256, 64, 3, 2, 1><<<dim3(98, 2, 3), 256, 0, stream>>>(
      I3h, I3l, w4h, w4l, nullptr, nullptr, nullptr, part);
  l4_finish<<<(1568 * 128 + 255) / 256, 256, 0, stream>>>(part, fb4, I4h, I4l, feat);

  // RPN: split-tap x9 -> partials, then finish
  rpn_partial<<<dim3(13, 4, 9), 256, 0, stream>>>(I4h, I4l, wrh, wrl, part);
  rpn_finish<<<(800 * 128 + 255) / 256, 256, 0, stream>>>(part, rpw_b, rp512);

  heads_kernel<<<(12000 + 255) / 256, 256, 0, stream>>>(rp512, cls_w, cls_b, reg_w, reg_b, out);
  fc_kernel<<<dim3(32, 20), 256, 0, stream>>>(feat, fc_w, fc_b, out);
  bbox_nms_kernel<<<BATCH, 128, 0, stream>>>(out);
}